// Round 1
// baseline (542.808 us; speedup 1.0000x reference)
//
#include <hip/hip_runtime.h>
#include <hip/hip_bf16.h>
#include <cstdint>

typedef __attribute__((ext_vector_type(4))) float f32x4;
typedef __attribute__((ext_vector_type(8))) __bf16 bf16x8;
typedef __attribute__((ext_vector_type(4))) __bf16 bf16x4;

#define EPI_BF16 0
#define EPI_GELU 1
#define EPI_RES  2

__device__ __forceinline__ void gll16(const void* g, void* l) {
  __builtin_amdgcn_global_load_lds((__attribute__((address_space(1))) void*)(g),
                                   (__attribute__((address_space(3))) void*)(l), 16, 0, 0);
}

// ---------------- weight convert + transpose: W[K,N] fp32 -> WT[N,K] bf16 ----------------
__global__ __launch_bounds__(256)
void convT(const float* __restrict__ W, __bf16* __restrict__ WT, int Kd, int Nd)
{
  __shared__ __bf16 t[64][72];
  const int tid = threadIdx.x;
  const int n0 = blockIdx.x * 64, k0 = blockIdx.y * 64;
#pragma unroll
  for (int i = 0; i < 4; ++i) {
    const int c = i * 256 + tid;
    const int r = c >> 4, cc = (c & 15) * 4;
    const float4 v = *(const float4*)(W + (size_t)(k0 + r) * Nd + n0 + cc);
    bf16x4 tv; tv[0] = (__bf16)v.x; tv[1] = (__bf16)v.y; tv[2] = (__bf16)v.z; tv[3] = (__bf16)v.w;
    *(bf16x4*)&t[r][cc] = tv;
  }
  __syncthreads();
#pragma unroll
  for (int i = 0; i < 2; ++i) {
    const int c = i * 256 + tid;
    const int n = c >> 3, s = (c & 7) * 8;
    bf16x8 o;
#pragma unroll
    for (int j = 0; j < 8; ++j) o[j] = t[s + j][n];
    *(bf16x8*)(WT + (size_t)(n0 + n) * Kd + k0 + s) = o;
  }
}

// ---------------- LayerNorm rows of 1024, fp32 in -> bf16 out ----------------
__global__ __launch_bounds__(256)
void ln_rows(const float* __restrict__ x, const float* __restrict__ g,
             const float* __restrict__ b, __bf16* __restrict__ out)
{
  const int row = blockIdx.x;
  const int tid = threadIdx.x;
  const float4 v = *(const float4*)(x + (size_t)row * 1024 + tid * 4);
  float s = v.x + v.y + v.z + v.w;
  float q = v.x * v.x + v.y * v.y + v.z * v.z + v.w * v.w;
#pragma unroll
  for (int o = 32; o; o >>= 1) { s += __shfl_xor(s, o); q += __shfl_xor(q, o); }
  __shared__ float red[8];
  const int wid = tid >> 6;
  if ((tid & 63) == 0) { red[wid] = s; red[4 + wid] = q; }
  __syncthreads();
  s = red[0] + red[1] + red[2] + red[3];
  q = red[4] + red[5] + red[6] + red[7];
  const float mu = s * (1.0f / 1024.0f);
  const float var = q * (1.0f / 1024.0f) - mu * mu;
  const float rs = rsqrtf(var + 1e-5f);
  bf16x4 o4;
#pragma unroll
  for (int i = 0; i < 4; ++i) {
    const int c = tid * 4 + i;
    const float xv = (&v.x)[i];
    o4[i] = (__bf16)((xv - mu) * rs * g[c] + b[c]);
  }
  *(bf16x4*)(out + (size_t)row * 1024 + tid * 4) = o4;
}

// ---------------- GEMM: C[M,N] = A[M,K](bf16) * W, W given as WT[N,K](bf16) ----------------
// EPI 0: out bf16 = acc + bias ; EPI 1: out bf16 = gelu(acc+bias) ; EPI 2: out f32 = acc+bias+R
template<int EPI>
__global__ __launch_bounds__(256)
void gemm_bt(const __bf16* __restrict__ A, const __bf16* __restrict__ BT,
             const float* __restrict__ bias, const float* __restrict__ R,
             void* __restrict__ Out, int M, int N, int K)
{
  const int tid = threadIdx.x;
  const int lane = tid & 63, wid = tid >> 6;
  const int l15 = lane & 15, lg = lane >> 4;
  const int wm = (wid >> 1) * 64, wn = (wid & 1) * 64;
  const int rowBase = blockIdx.y * 128, colBase = blockIdx.x * 128;
  __shared__ __bf16 As[128 * 32];
  __shared__ __bf16 Bs[128 * 32];
  f32x4 acc[4][4] = {};

  for (int k0 = 0; k0 < K; k0 += 32) {
#pragma unroll
    for (int i = 0; i < 2; ++i) {
      const int c = i * 256 + tid;
      const int r = c >> 2, s = (c & 3) * 8;
      gll16(A + (size_t)(rowBase + r) * K + (k0 + s), As + c * 8);
    }
#pragma unroll
    for (int i = 0; i < 2; ++i) {
      const int c = i * 256 + tid;
      const int r = c >> 2, s = (c & 3) * 8;
      gll16(BT + (size_t)(colBase + r) * K + (k0 + s), Bs + c * 8);
    }
    __syncthreads();
    bf16x8 af[4], bfr[4];
#pragma unroll
    for (int m = 0; m < 4; ++m) af[m] = *(const bf16x8*)(As + (wm + m * 16 + l15) * 32 + lg * 8);
#pragma unroll
    for (int n = 0; n < 4; ++n) bfr[n] = *(const bf16x8*)(Bs + (wn + n * 16 + l15) * 32 + lg * 8);
#pragma unroll
    for (int m = 0; m < 4; ++m)
#pragma unroll
      for (int n = 0; n < 4; ++n)
        acc[m][n] = __builtin_amdgcn_mfma_f32_16x16x32_bf16(af[m], bfr[n], acc[m][n], 0, 0, 0);
    __syncthreads();
  }
#pragma unroll
  for (int m = 0; m < 4; ++m) {
#pragma unroll
    for (int n = 0; n < 4; ++n) {
      const int col = colBase + wn + n * 16 + l15;
      const float bb = bias[col];
#pragma unroll
      for (int i = 0; i < 4; ++i) {
        const int row = rowBase + wm + m * 16 + lg * 4 + i;
        float v = acc[m][n][i] + bb;
        if constexpr (EPI == EPI_GELU) {
          v = 0.5f * v * (1.0f + erff(v * 0.70710678118654752f));
          ((__bf16*)Out)[(size_t)row * N + col] = (__bf16)v;
        } else if constexpr (EPI == EPI_BF16) {
          ((__bf16*)Out)[(size_t)row * N + col] = (__bf16)v;
        } else {
          v += R[(size_t)row * N + col];
          ((float*)Out)[(size_t)row * N + col] = v;
        }
      }
    }
  }
}

// ---------------- rearrange qkv[4096,3072] -> Q[bh,t,d], K[bh,t,d], VT[bh,d,t] ----------------
__global__ __launch_bounds__(256)
void rearrange(const __bf16* __restrict__ qkv, __bf16* __restrict__ Q,
               __bf16* __restrict__ Kb, __bf16* __restrict__ VT)
{
  __shared__ __bf16 vt[64][72];
  const int tid = threadIdx.x;
  const int bid = blockIdx.x;
  const int bh = bid >> 5, tt = bid & 31;
  const int b = bh >> 4, h = bh & 15;
  const int t0 = tt * 64;
#pragma unroll
  for (int i = 0; i < 2; ++i) {
    const int c = i * 256 + tid;
    const int tk = c >> 3, d0 = (c & 7) * 8;
    const size_t srow = (size_t)(b * 2048 + t0 + tk) * 3072 + h * 64 + d0;
    const size_t drow = (size_t)(bh * 2048 + t0 + tk) * 64 + d0;
    *(bf16x8*)(Q + drow) = *(const bf16x8*)(qkv + srow);
    *(bf16x8*)(Kb + drow) = *(const bf16x8*)(qkv + srow + 1024);
    *(bf16x8*)&vt[tk][d0] = *(const bf16x8*)(qkv + srow + 2048);
  }
  __syncthreads();
#pragma unroll
  for (int i = 0; i < 2; ++i) {
    const int c = i * 256 + tid;
    const int d = c >> 3, s = (c & 7) * 8;
    bf16x8 o;
#pragma unroll
    for (int j = 0; j < 8; ++j) o[j] = vt[s + j][d];
    *(bf16x8*)(VT + (size_t)(bh * 64 + d) * 2048 + t0 + s) = o;
  }
}

// ---------------- flash attention, causal; QBLK=128 (4 waves x 32 rows), KVBLK=64 ----------------
__global__ __launch_bounds__(256)
void attn(const __bf16* __restrict__ Q, const __bf16* __restrict__ K,
          const __bf16* __restrict__ VT, __bf16* __restrict__ O)
{
  const int bid = blockIdx.x;
  const int bh = bid >> 4, qt = bid & 15;
  const int tid = threadIdx.x;
  const int lane = tid & 63, w = tid >> 6;
  const int l15 = lane & 15, lg = lane >> 4;
  __shared__ __bf16 Ks[64 * 64];
  __shared__ __bf16 Vs[64 * 64];
  __shared__ __bf16 Ps[4][32 * 72];
  const size_t base = (size_t)bh * 2048 * 64;
  const int qrow0 = qt * 128 + w * 32;
  bf16x8 aq[2][2];
#pragma unroll
  for (int m = 0; m < 2; ++m)
#pragma unroll
    for (int kk = 0; kk < 2; ++kk)
      aq[m][kk] = *(const bf16x8*)(Q + base + (size_t)(qrow0 + m * 16 + l15) * 64 + kk * 32 + lg * 8);
  f32x4 oacc[2][4] = {};
  float mst[2][4], lst[2][4];
#pragma unroll
  for (int m = 0; m < 2; ++m)
#pragma unroll
    for (int i = 0; i < 4; ++i) { mst[m][i] = -INFINITY; lst[m][i] = 0.0f; }

  const int jmax = 2 * qt + 1;
  for (int j = 0; j <= jmax; ++j) {
#pragma unroll
    for (int i = 0; i < 2; ++i) {
      const int c = i * 256 + tid;
      const int r = c >> 3, s = (c & 7) * 8;
      gll16(K + base + (size_t)(j * 64 + r) * 64 + s, Ks + c * 8);
      gll16(VT + base + (size_t)r * 2048 + (j * 64 + s), Vs + c * 8);
    }
    __syncthreads();
    // S = Q K^T
    f32x4 sf[2][4];
#pragma unroll
    for (int m = 0; m < 2; ++m)
#pragma unroll
      for (int n = 0; n < 4; ++n) {
        f32x4 z = {};
#pragma unroll
        for (int kk = 0; kk < 2; ++kk) {
          bf16x8 bk = *(const bf16x8*)(Ks + (n * 16 + l15) * 64 + kk * 32 + lg * 8);
          z = __builtin_amdgcn_mfma_f32_16x16x32_bf16(aq[m][kk], bk, z, 0, 0, 0);
        }
        sf[m][n] = z;
      }
    const bool diag = (j >= 2 * qt);
#pragma unroll
    for (int m = 0; m < 2; ++m)
#pragma unroll
      for (int n = 0; n < 4; ++n)
#pragma unroll
        for (int i = 0; i < 4; ++i) {
          float sv = sf[m][n][i] * 0.125f;
          if (diag) {
            const int kv = j * 64 + n * 16 + l15;
            const int qr = qrow0 + m * 16 + lg * 4 + i;
            if (kv > qr) sv = -INFINITY;
          }
          sf[m][n][i] = sv;
        }
    // online softmax (rows live in 16-lane groups; reduce over l15)
#pragma unroll
    for (int m = 0; m < 2; ++m) {
      float mx[4], cf[4], rsum[4];
#pragma unroll
      for (int i = 0; i < 4; ++i) {
        float t = fmaxf(fmaxf(sf[m][0][i], sf[m][1][i]), fmaxf(sf[m][2][i], sf[m][3][i]));
#pragma unroll
        for (int o = 1; o < 16; o <<= 1) t = fmaxf(t, __shfl_xor(t, o));
        mx[i] = fmaxf(t, mst[m][i]);
        cf[i] = __expf(mst[m][i] - mx[i]);
        rsum[i] = 0.0f;
      }
#pragma unroll
      for (int n = 0; n < 4; ++n)
#pragma unroll
        for (int i = 0; i < 4; ++i) {
          const float p = __expf(sf[m][n][i] - mx[i]);
          rsum[i] += p;
          Ps[w][(m * 16 + lg * 4 + i) * 72 + n * 16 + l15] = (__bf16)p;
        }
#pragma unroll
      for (int i = 0; i < 4; ++i) {
        float t = rsum[i];
#pragma unroll
        for (int o = 1; o < 16; o <<= 1) t += __shfl_xor(t, o);
        lst[m][i] = lst[m][i] * cf[i] + t;
        mst[m][i] = mx[i];
      }
#pragma unroll
      for (int n = 0; n < 4; ++n)
#pragma unroll
        for (int i = 0; i < 4; ++i) oacc[m][n][i] *= cf[i];
    }
    // O += P V  (A-frags from Ps, B-frags from Vs=V^T tile)
#pragma unroll
    for (int t = 0; t < 2; ++t) {
      bf16x8 ap0 = *(const bf16x8*)(Ps[w] + (0 * 16 + l15) * 72 + t * 32 + lg * 8);
      bf16x8 ap1 = *(const bf16x8*)(Ps[w] + (1 * 16 + l15) * 72 + t * 32 + lg * 8);
#pragma unroll
      for (int n = 0; n < 4; ++n) {
        bf16x8 bv = *(const bf16x8*)(Vs + (n * 16 + l15) * 64 + t * 32 + lg * 8);
        oacc[0][n] = __builtin_amdgcn_mfma_f32_16x16x32_bf16(ap0, bv, oacc[0][n], 0, 0, 0);
        oacc[1][n] = __builtin_amdgcn_mfma_f32_16x16x32_bf16(ap1, bv, oacc[1][n], 0, 0, 0);
      }
    }
    __syncthreads();
  }
  const int b = bh >> 4, h = bh & 15;
#pragma unroll
  for (int m = 0; m < 2; ++m)
#pragma unroll
    for (int i = 0; i < 4; ++i) {
      const float inv = 1.0f / lst[m][i];
      const int t = qrow0 + m * 16 + lg * 4 + i;
#pragma unroll
      for (int n = 0; n < 4; ++n)
        O[(size_t)(b * 2048 + t) * 1024 + h * 64 + n * 16 + l15] = (__bf16)(oacc[m][n][i] * inv);
    }
}

// ---------------- host ----------------
extern "C" void kernel_launch(void* const* d_in, const int* in_sizes, int n_in,
                              void* d_out, int out_size, void* d_ws, size_t ws_size,
                              hipStream_t stream)
{
  const float* x      = (const float*)d_in[0];
  const float* ln1_g  = (const float*)d_in[1];
  const float* ln1_b  = (const float*)d_in[2];
  const float* qkv_w  = (const float*)d_in[3];
  const float* qkv_b  = (const float*)d_in[4];
  const float* proj_w = (const float*)d_in[5];
  const float* proj_b = (const float*)d_in[6];
  const float* ln2_g  = (const float*)d_in[7];
  const float* ln2_b  = (const float*)d_in[8];
  const float* mlp_w1 = (const float*)d_in[9];
  const float* mlp_b1 = (const float*)d_in[10];
  const float* mlp_w2 = (const float*)d_in[11];
  const float* mlp_b2 = (const float*)d_in[12];

  char* ws = (char*)d_ws;
  __bf16* qkvT  = (__bf16*)(ws + 0);          //  6291456
  __bf16* projT = (__bf16*)(ws + 6291456);    //  2097152
  __bf16* w1T   = (__bf16*)(ws + 8388608);    //  8388608
  __bf16* w2T   = (__bf16*)(ws + 16777216);   //  8388608
  __bf16* h1    = (__bf16*)(ws + 25165824);   //  8388608
  __bf16* qkv   = (__bf16*)(ws + 33554432);   // 25165824 (dead after rearrange)
  __bf16* act1  = (__bf16*)(ws + 33554432);   // 33554432, aliases qkv+Qb (both dead by MLP1)
  __bf16* Qb    = (__bf16*)(ws + 58720256);   //  8388608
  __bf16* Kb    = (__bf16*)(ws + 67108864);   //  8388608
  __bf16* VTb   = (__bf16*)(ws + 75497472);   //  8388608
  __bf16* attO  = (__bf16*)(ws + 83886080);   //  8388608
  float*  x2    = (float*) (ws + 92274688);   // 16777216
  __bf16* h2    = (__bf16*)(ws + 109051904);  //  8388608  (total 117440512 B)

  convT<<<dim3(48, 16), 256, 0, stream>>>(qkv_w, qkvT, 1024, 3072);
  convT<<<dim3(16, 16), 256, 0, stream>>>(proj_w, projT, 1024, 1024);
  convT<<<dim3(64, 16), 256, 0, stream>>>(mlp_w1, w1T, 1024, 4096);
  convT<<<dim3(16, 64), 256, 0, stream>>>(mlp_w2, w2T, 4096, 1024);

  ln_rows<<<4096, 256, 0, stream>>>(x, ln1_g, ln1_b, h1);
  gemm_bt<EPI_BF16><<<dim3(24, 32), 256, 0, stream>>>(h1, qkvT, qkv_b, nullptr, qkv, 4096, 3072, 1024);
  rearrange<<<1024, 256, 0, stream>>>(qkv, Qb, Kb, VTb);
  attn<<<512, 256, 0, stream>>>(Qb, Kb, VTb, attO);
  gemm_bt<EPI_RES><<<dim3(8, 32), 256, 0, stream>>>(attO, projT, proj_b, x, x2, 4096, 1024, 1024);
  ln_rows<<<4096, 256, 0, stream>>>(x2, ln2_g, ln2_b, h2);
  gemm_bt<EPI_GELU><<<dim3(32, 32), 256, 0, stream>>>(h2, w1T, mlp_b1, nullptr, act1, 4096, 4096, 1024);
  gemm_bt<EPI_RES><<<dim3(8, 32), 256, 0, stream>>>(act1, w2T, mlp_b2, x2, (float*)d_out, 4096, 1024, 4096);
}

// Round 2
// 485.785 us; speedup vs baseline: 1.1174x; 1.1174x over previous
//
#include <hip/hip_runtime.h>
#include <hip/hip_bf16.h>
#include <cstdint>

typedef __attribute__((ext_vector_type(4))) float f32x4;
typedef __attribute__((ext_vector_type(8))) __bf16 bf16x8;
typedef __attribute__((ext_vector_type(4))) __bf16 bf16x4;

#define EPI_BF16 0
#define EPI_GELU 1
#define EPI_RES  2

__device__ __forceinline__ void gll16(const void* g, void* l) {
  __builtin_amdgcn_global_load_lds((__attribute__((address_space(1))) void*)(g),
                                   (__attribute__((address_space(3))) void*)(l), 16, 0, 0);
}

// ---------------- weight convert + transpose: W[K,N] fp32 -> WT[N,K] bf16 ----------------
__global__ __launch_bounds__(256)
void convT(const float* __restrict__ W, __bf16* __restrict__ WT, int Kd, int Nd)
{
  __shared__ __bf16 t[64][72];
  const int tid = threadIdx.x;
  const int n0 = blockIdx.x * 64, k0 = blockIdx.y * 64;
#pragma unroll
  for (int i = 0; i < 4; ++i) {
    const int c = i * 256 + tid;
    const int r = c >> 4, cc = (c & 15) * 4;
    const float4 v = *(const float4*)(W + (size_t)(k0 + r) * Nd + n0 + cc);
    bf16x4 tv; tv[0] = (__bf16)v.x; tv[1] = (__bf16)v.y; tv[2] = (__bf16)v.z; tv[3] = (__bf16)v.w;
    *(bf16x4*)&t[r][cc] = tv;
  }
  __syncthreads();
#pragma unroll
  for (int i = 0; i < 2; ++i) {
    const int c = i * 256 + tid;
    const int n = c >> 3, s = (c & 7) * 8;
    bf16x8 o;
#pragma unroll
    for (int j = 0; j < 8; ++j) o[j] = t[s + j][n];
    *(bf16x8*)(WT + (size_t)(n0 + n) * Kd + k0 + s) = o;
  }
}

// ---------------- LayerNorm rows of 1024, fp32 in -> bf16 out ----------------
__global__ __launch_bounds__(256)
void ln_rows(const float* __restrict__ x, const float* __restrict__ g,
             const float* __restrict__ b, __bf16* __restrict__ out)
{
  const int row = blockIdx.x;
  const int tid = threadIdx.x;
  const float4 v = *(const float4*)(x + (size_t)row * 1024 + tid * 4);
  float s = v.x + v.y + v.z + v.w;
  float q = v.x * v.x + v.y * v.y + v.z * v.z + v.w * v.w;
#pragma unroll
  for (int o = 32; o; o >>= 1) { s += __shfl_xor(s, o); q += __shfl_xor(q, o); }
  __shared__ float red[8];
  const int wid = tid >> 6;
  if ((tid & 63) == 0) { red[wid] = s; red[4 + wid] = q; }
  __syncthreads();
  s = red[0] + red[1] + red[2] + red[3];
  q = red[4] + red[5] + red[6] + red[7];
  const float mu = s * (1.0f / 1024.0f);
  const float var = q * (1.0f / 1024.0f) - mu * mu;
  const float rs = rsqrtf(var + 1e-5f);
  bf16x4 o4;
#pragma unroll
  for (int i = 0; i < 4; ++i) {
    const int c = tid * 4 + i;
    const float xv = (&v.x)[i];
    o4[i] = (__bf16)((xv - mu) * rs * g[c] + b[c]);
  }
  *(bf16x4*)(out + (size_t)row * 1024 + tid * 4) = o4;
}

// ---------------- GEMM: C[M,N] = A[M,K](bf16) * W, W given as WT[N,K](bf16) ----------------
template<int EPI>
__global__ __launch_bounds__(256)
void gemm_bt(const __bf16* __restrict__ A, const __bf16* __restrict__ BT,
             const float* __restrict__ bias, const float* __restrict__ R,
             void* __restrict__ Out, int M, int N, int K)
{
  const int tid = threadIdx.x;
  const int lane = tid & 63, wid = tid >> 6;
  const int l15 = lane & 15, lg = lane >> 4;
  const int wm = (wid >> 1) * 64, wn = (wid & 1) * 64;
  const int rowBase = blockIdx.y * 128, colBase = blockIdx.x * 128;
  __shared__ __bf16 As[128 * 32];
  __shared__ __bf16 Bs[128 * 32];
  f32x4 acc[4][4] = {};

  for (int k0 = 0; k0 < K; k0 += 32) {
#pragma unroll
    for (int i = 0; i < 2; ++i) {
      const int c = i * 256 + tid;
      const int r = c >> 2, s = (c & 3) * 8;
      gll16(A + (size_t)(rowBase + r) * K + (k0 + s), As + c * 8);
    }
#pragma unroll
    for (int i = 0; i < 2; ++i) {
      const int c = i * 256 + tid;
      const int r = c >> 2, s = (c & 3) * 8;
      gll16(BT + (size_t)(colBase + r) * K + (k0 + s), Bs + c * 8);
    }
    __syncthreads();
    bf16x8 af[4], bfr[4];
#pragma unroll
    for (int m = 0; m < 4; ++m) af[m] = *(const bf16x8*)(As + (wm + m * 16 + l15) * 32 + lg * 8);
#pragma unroll
    for (int n = 0; n < 4; ++n) bfr[n] = *(const bf16x8*)(Bs + (wn + n * 16 + l15) * 32 + lg * 8);
#pragma unroll
    for (int m = 0; m < 4; ++m)
#pragma unroll
      for (int n = 0; n < 4; ++n)
        acc[m][n] = __builtin_amdgcn_mfma_f32_16x16x32_bf16(af[m], bfr[n], acc[m][n], 0, 0, 0);
    __syncthreads();
  }
#pragma unroll
  for (int m = 0; m < 4; ++m) {
#pragma unroll
    for (int n = 0; n < 4; ++n) {
      const int col = colBase + wn + n * 16 + l15;
      const float bb = bias[col];
#pragma unroll
      for (int i = 0; i < 4; ++i) {
        const int row = rowBase + wm + m * 16 + lg * 4 + i;
        float v = acc[m][n][i] + bb;
        if constexpr (EPI == EPI_GELU) {
          v = 0.5f * v * (1.0f + erff(v * 0.70710678118654752f));
          ((__bf16*)Out)[(size_t)row * N + col] = (__bf16)v;
        } else if constexpr (EPI == EPI_BF16) {
          ((__bf16*)Out)[(size_t)row * N + col] = (__bf16)v;
        } else {
          v += R[(size_t)row * N + col];
          ((float*)Out)[(size_t)row * N + col] = v;
        }
      }
    }
  }
}

// ---------------- rearrange qkv[4096,3072] -> Q[bh,t,d], K[bh,t,d], VT[bh,d,t] ----------------
__global__ __launch_bounds__(256)
void rearrange(const __bf16* __restrict__ qkv, __bf16* __restrict__ Q,
               __bf16* __restrict__ Kb, __bf16* __restrict__ VT)
{
  __shared__ __bf16 vt[64][72];
  const int tid = threadIdx.x;
  const int bid = blockIdx.x;
  const int bh = bid >> 5, tt = bid & 31;
  const int b = bh >> 4, h = bh & 15;
  const int t0 = tt * 64;
#pragma unroll
  for (int i = 0; i < 2; ++i) {
    const int c = i * 256 + tid;
    const int tk = c >> 3, d0 = (c & 7) * 8;
    const size_t srow = (size_t)(b * 2048 + t0 + tk) * 3072 + h * 64 + d0;
    const size_t drow = (size_t)(bh * 2048 + t0 + tk) * 64 + d0;
    *(bf16x8*)(Q + drow) = *(const bf16x8*)(qkv + srow);
    *(bf16x8*)(Kb + drow) = *(const bf16x8*)(qkv + srow + 1024);
    *(bf16x8*)&vt[tk][d0] = *(const bf16x8*)(qkv + srow + 2048);
  }
  __syncthreads();
#pragma unroll
  for (int i = 0; i < 2; ++i) {
    const int c = i * 256 + tid;
    const int d = c >> 3, s = (c & 7) * 8;
    bf16x8 o;
#pragma unroll
    for (int j = 0; j < 8; ++j) o[j] = vt[s + j][d];
    *(bf16x8*)(VT + (size_t)(bh * 64 + d) * 2048 + t0 + s) = o;
  }
}

// ---------------- flash attention, causal; QBLK=64 (4 waves x 16 rows), KVBLK=64 ----------------
// K/V LDS tiles are XOR-swizzled (linear LDS dest for global_load_lds; swizzle applied by
// permuting the GLOBAL source offset, matching swizzle on the ds_read side).
__global__ __launch_bounds__(256)
void attn(const __bf16* __restrict__ Q, const __bf16* __restrict__ K,
          const __bf16* __restrict__ VT, __bf16* __restrict__ O)
{
  const int bid = blockIdx.x;
  const int bh = bid >> 5, qt = bid & 31;
  const int tid = threadIdx.x;
  const int lane = tid & 63, w = tid >> 6;
  const int l15 = lane & 15, lg = lane >> 4;
  __shared__ __bf16 Ks[64 * 64];
  __shared__ __bf16 Vs[64 * 64];
  __shared__ __bf16 Ps[4][16 * 72];
  const size_t base = (size_t)bh * 2048 * 64;
  const int qrow0 = qt * 64 + w * 16;
  bf16x8 aq[2];
#pragma unroll
  for (int kk = 0; kk < 2; ++kk)
    aq[kk] = *(const bf16x8*)(Q + base + (size_t)(qrow0 + l15) * 64 + kk * 32 + lg * 8);
  f32x4 oacc[4] = {};
  float mst[4], lst[4];
#pragma unroll
  for (int i = 0; i < 4; ++i) { mst[i] = -INFINITY; lst[i] = 0.0f; }

  const int xsw = (l15 & 7) << 3;   // element-offset XOR for swizzled ds_read

  for (int j = 0; j <= qt; ++j) {
#pragma unroll
    for (int i = 0; i < 2; ++i) {
      const int c = i * 256 + tid;
      const int r = c >> 3;
      const int sc = ((c & 7) ^ (r & 7)) * 8;   // pre-swizzled global source column
      gll16(K + base + (size_t)(j * 64 + r) * 64 + sc, Ks + c * 8);
      gll16(VT + base + (size_t)r * 2048 + j * 64 + sc, Vs + c * 8);
    }
    __syncthreads();
    // S = Q K^T
    f32x4 sf[4];
#pragma unroll
    for (int n = 0; n < 4; ++n) {
      f32x4 z = {};
#pragma unroll
      for (int kk = 0; kk < 2; ++kk) {
        bf16x8 bk = *(const bf16x8*)(Ks + (n * 16 + l15) * 64 + ((kk * 32 + lg * 8) ^ xsw));
        z = __builtin_amdgcn_mfma_f32_16x16x32_bf16(aq[kk], bk, z, 0, 0, 0);
      }
      sf[n] = z;
    }
    const bool diag = (j == qt);
#pragma unroll
    for (int n = 0; n < 4; ++n)
#pragma unroll
      for (int i = 0; i < 4; ++i) {
        float sv = sf[n][i] * 0.125f;
        if (diag) {
          const int kv = j * 64 + n * 16 + l15;
          const int qr = qrow0 + lg * 4 + i;
          if (kv > qr) sv = -INFINITY;
        }
        sf[n][i] = sv;
      }
    // online softmax (rows live across l15; reduce within 16-lane group)
    float mx[4], cf[4], rsum[4];
#pragma unroll
    for (int i = 0; i < 4; ++i) {
      float t = fmaxf(fmaxf(sf[0][i], sf[1][i]), fmaxf(sf[2][i], sf[3][i]));
#pragma unroll
      for (int o = 1; o < 16; o <<= 1) t = fmaxf(t, __shfl_xor(t, o));
      mx[i] = fmaxf(t, mst[i]);
      cf[i] = __expf(mst[i] - mx[i]);
      rsum[i] = 0.0f;
    }
#pragma unroll
    for (int n = 0; n < 4; ++n)
#pragma unroll
      for (int i = 0; i < 4; ++i) {
        const float p = __expf(sf[n][i] - mx[i]);
        rsum[i] += p;
        Ps[w][(lg * 4 + i) * 72 + n * 16 + l15] = (__bf16)p;
      }
#pragma unroll
    for (int i = 0; i < 4; ++i) {
      float t = rsum[i];
#pragma unroll
      for (int o = 1; o < 16; o <<= 1) t += __shfl_xor(t, o);
      lst[i] = lst[i] * cf[i] + t;
      mst[i] = mx[i];
    }
#pragma unroll
    for (int n = 0; n < 4; ++n)
#pragma unroll
      for (int i = 0; i < 4; ++i) oacc[n][i] *= cf[i];
    // O += P V  (A-frags from Ps, B-frags from Vs = V^T tile)
#pragma unroll
    for (int t = 0; t < 2; ++t) {
      bf16x8 ap = *(const bf16x8*)(Ps[w] + l15 * 72 + t * 32 + lg * 8);
#pragma unroll
      for (int n = 0; n < 4; ++n) {
        bf16x8 bv = *(const bf16x8*)(Vs + (n * 16 + l15) * 64 + ((t * 32 + lg * 8) ^ xsw));
        oacc[n] = __builtin_amdgcn_mfma_f32_16x16x32_bf16(ap, bv, oacc[n], 0, 0, 0);
      }
    }
    __syncthreads();
  }
  const int b = bh >> 4, h = bh & 15;
#pragma unroll
  for (int i = 0; i < 4; ++i) {
    const float inv = 1.0f / lst[i];
    const int t = qrow0 + lg * 4 + i;
#pragma unroll
    for (int n = 0; n < 4; ++n)
      O[(size_t)(b * 2048 + t) * 1024 + h * 64 + n * 16 + l15] = (__bf16)(oacc[n][i] * inv);
  }
}

// ---------------- host ----------------
extern "C" void kernel_launch(void* const* d_in, const int* in_sizes, int n_in,
                              void* d_out, int out_size, void* d_ws, size_t ws_size,
                              hipStream_t stream)
{
  const float* x      = (const float*)d_in[0];
  const float* ln1_g  = (const float*)d_in[1];
  const float* ln1_b  = (const float*)d_in[2];
  const float* qkv_w  = (const float*)d_in[3];
  const float* qkv_b  = (const float*)d_in[4];
  const float* proj_w = (const float*)d_in[5];
  const float* proj_b = (const float*)d_in[6];
  const float* ln2_g  = (const float*)d_in[7];
  const float* ln2_b  = (const float*)d_in[8];
  const float* mlp_w1 = (const float*)d_in[9];
  const float* mlp_b1 = (const float*)d_in[10];
  const float* mlp_w2 = (const float*)d_in[11];
  const float* mlp_b2 = (const float*)d_in[12];

  char* ws = (char*)d_ws;
  __bf16* qkvT  = (__bf16*)(ws + 0);          //  6291456
  __bf16* projT = (__bf16*)(ws + 6291456);    //  2097152
  __bf16* w1T   = (__bf16*)(ws + 8388608);    //  8388608
  __bf16* w2T   = (__bf16*)(ws + 16777216);   //  8388608
  __bf16* h1    = (__bf16*)(ws + 25165824);   //  8388608
  __bf16* qkv   = (__bf16*)(ws + 33554432);   // 25165824 (dead after rearrange)
  __bf16* act1  = (__bf16*)(ws + 33554432);   // 33554432, aliases qkv+Qb (both dead by MLP1)
  __bf16* Qb    = (__bf16*)(ws + 58720256);   //  8388608
  __bf16* Kb    = (__bf16*)(ws + 67108864);   //  8388608
  __bf16* VTb   = (__bf16*)(ws + 75497472);   //  8388608
  __bf16* attO  = (__bf16*)(ws + 83886080);   //  8388608
  float*  x2    = (float*) (ws + 92274688);   // 16777216
  __bf16* h2    = (__bf16*)(ws + 109051904);  //  8388608  (total 117440512 B)

  convT<<<dim3(48, 16), 256, 0, stream>>>(qkv_w, qkvT, 1024, 3072);
  convT<<<dim3(16, 16), 256, 0, stream>>>(proj_w, projT, 1024, 1024);
  convT<<<dim3(64, 16), 256, 0, stream>>>(mlp_w1, w1T, 1024, 4096);
  convT<<<dim3(16, 64), 256, 0, stream>>>(mlp_w2, w2T, 4096, 1024);

  ln_rows<<<4096, 256, 0, stream>>>(x, ln1_g, ln1_b, h1);
  gemm_bt<EPI_BF16><<<dim3(24, 32), 256, 0, stream>>>(h1, qkvT, qkv_b, nullptr, qkv, 4096, 3072, 1024);
  rearrange<<<1024, 256, 0, stream>>>(qkv, Qb, Kb, VTb);
  attn<<<1024, 256, 0, stream>>>(Qb, Kb, VTb, attO);
  gemm_bt<EPI_RES><<<dim3(8, 32), 256, 0, stream>>>(attO, projT, proj_b, x, x2, 4096, 1024, 1024);
  ln_rows<<<4096, 256, 0, stream>>>(x2, ln2_g, ln2_b, h2);
  gemm_bt<EPI_GELU><<<dim3(32, 32), 256, 0, stream>>>(h2, w1T, mlp_b1, nullptr, act1, 4096, 4096, 1024);
  gemm_bt<EPI_RES><<<dim3(8, 32), 256, 0, stream>>>(act1, w2T, mlp_b2, x2, (float*)d_out, 4096, 1024, 4096);
}

// Round 4
// 443.560 us; speedup vs baseline: 1.2238x; 1.0952x over previous
//
#include <hip/hip_runtime.h>
#include <hip/hip_bf16.h>
#include <cstdint>

typedef __attribute__((ext_vector_type(4))) float f32x4;
typedef __attribute__((ext_vector_type(16))) float f32x16;
typedef __attribute__((ext_vector_type(8))) __bf16 bf16x8;
typedef __attribute__((ext_vector_type(4))) __bf16 bf16x4;
typedef __attribute__((ext_vector_type(4))) uint32_t u32x4;
typedef __attribute__((ext_vector_type(2))) unsigned int u32x2;

#define EPI_BF16 0
#define EPI_GELU 1
#define EPI_RES  2

__device__ __forceinline__ void gll16(const void* g, void* l) {
  __builtin_amdgcn_global_load_lds((__attribute__((address_space(1))) void*)(g),
                                   (__attribute__((address_space(3))) void*)(l), 16, 0, 0);
}

// ---------------- weight convert + transpose: W[K,N] fp32 -> WT[N,K] bf16 ----------------
__global__ __launch_bounds__(256)
void convT(const float* __restrict__ W, __bf16* __restrict__ WT, int Kd, int Nd)
{
  __shared__ __bf16 t[64][72];
  const int tid = threadIdx.x;
  const int n0 = blockIdx.x * 64, k0 = blockIdx.y * 64;
#pragma unroll
  for (int i = 0; i < 4; ++i) {
    const int c = i * 256 + tid;
    const int r = c >> 4, cc = (c & 15) * 4;
    const float4 v = *(const float4*)(W + (size_t)(k0 + r) * Nd + n0 + cc);
    bf16x4 tv; tv[0] = (__bf16)v.x; tv[1] = (__bf16)v.y; tv[2] = (__bf16)v.z; tv[3] = (__bf16)v.w;
    *(bf16x4*)&t[r][cc] = tv;
  }
  __syncthreads();
#pragma unroll
  for (int i = 0; i < 2; ++i) {
    const int c = i * 256 + tid;
    const int n = c >> 3, s = (c & 7) * 8;
    bf16x8 o;
#pragma unroll
    for (int j = 0; j < 8; ++j) o[j] = t[s + j][n];
    *(bf16x8*)(WT + (size_t)(n0 + n) * Kd + k0 + s) = o;
  }
}

// ---------------- LayerNorm rows of 1024, fp32 in -> bf16 out ----------------
__global__ __launch_bounds__(256)
void ln_rows(const float* __restrict__ x, const float* __restrict__ g,
             const float* __restrict__ b, __bf16* __restrict__ out)
{
  const int row = blockIdx.x;
  const int tid = threadIdx.x;
  const float4 v = *(const float4*)(x + (size_t)row * 1024 + tid * 4);
  float s = v.x + v.y + v.z + v.w;
  float q = v.x * v.x + v.y * v.y + v.z * v.z + v.w * v.w;
#pragma unroll
  for (int o = 32; o; o >>= 1) { s += __shfl_xor(s, o); q += __shfl_xor(q, o); }
  __shared__ float red[8];
  const int wid = tid >> 6;
  if ((tid & 63) == 0) { red[wid] = s; red[4 + wid] = q; }
  __syncthreads();
  s = red[0] + red[1] + red[2] + red[3];
  q = red[4] + red[5] + red[6] + red[7];
  const float mu = s * (1.0f / 1024.0f);
  const float var = q * (1.0f / 1024.0f) - mu * mu;
  const float rs = rsqrtf(var + 1e-5f);
  bf16x4 o4;
#pragma unroll
  for (int i = 0; i < 4; ++i) {
    const int c = tid * 4 + i;
    const float xv = (&v.x)[i];
    o4[i] = (__bf16)((xv - mu) * rs * g[c] + b[c]);
  }
  *(bf16x4*)(out + (size_t)row * 1024 + tid * 4) = o4;
}

// ---------------- GEMM: C[M,N] = A[M,K](bf16) * W, W given as WT[N,K](bf16) ----------------
template<int EPI>
__global__ __launch_bounds__(256)
void gemm_bt(const __bf16* __restrict__ A, const __bf16* __restrict__ BT,
             const float* __restrict__ bias, const float* __restrict__ R,
             void* __restrict__ Out, int M, int N, int K)
{
  const int tid = threadIdx.x;
  const int lane = tid & 63, wid = tid >> 6;
  const int l15 = lane & 15, lg = lane >> 4;
  const int wm = (wid >> 1) * 64, wn = (wid & 1) * 64;
  const int rowBase = blockIdx.y * 128, colBase = blockIdx.x * 128;
  __shared__ __bf16 As[128 * 32];
  __shared__ __bf16 Bs[128 * 32];
  f32x4 acc[4][4] = {};

  for (int k0 = 0; k0 < K; k0 += 32) {
#pragma unroll
    for (int i = 0; i < 2; ++i) {
      const int c = i * 256 + tid;
      const int r = c >> 2, s = (c & 3) * 8;
      gll16(A + (size_t)(rowBase + r) * K + (k0 + s), As + c * 8);
    }
#pragma unroll
    for (int i = 0; i < 2; ++i) {
      const int c = i * 256 + tid;
      const int r = c >> 2, s = (c & 3) * 8;
      gll16(BT + (size_t)(colBase + r) * K + (k0 + s), Bs + c * 8);
    }
    __syncthreads();
    bf16x8 af[4], bfr[4];
#pragma unroll
    for (int m = 0; m < 4; ++m) af[m] = *(const bf16x8*)(As + (wm + m * 16 + l15) * 32 + lg * 8);
#pragma unroll
    for (int n = 0; n < 4; ++n) bfr[n] = *(const bf16x8*)(Bs + (wn + n * 16 + l15) * 32 + lg * 8);
#pragma unroll
    for (int m = 0; m < 4; ++m)
#pragma unroll
      for (int n = 0; n < 4; ++n)
        acc[m][n] = __builtin_amdgcn_mfma_f32_16x16x32_bf16(af[m], bfr[n], acc[m][n], 0, 0, 0);
    __syncthreads();
  }
#pragma unroll
  for (int m = 0; m < 4; ++m) {
#pragma unroll
    for (int n = 0; n < 4; ++n) {
      const int col = colBase + wn + n * 16 + l15;
      const float bb = bias[col];
#pragma unroll
      for (int i = 0; i < 4; ++i) {
        const int row = rowBase + wm + m * 16 + lg * 4 + i;
        float v = acc[m][n][i] + bb;
        if constexpr (EPI == EPI_GELU) {
          v = 0.5f * v * (1.0f + erff(v * 0.70710678118654752f));
          ((__bf16*)Out)[(size_t)row * N + col] = (__bf16)v;
        } else if constexpr (EPI == EPI_BF16) {
          ((__bf16*)Out)[(size_t)row * N + col] = (__bf16)v;
        } else {
          v += R[(size_t)row * N + col];
          ((float*)Out)[(size_t)row * N + col] = v;
        }
      }
    }
  }
}

// ---------------- rearrange qkv[4096,3072] -> Q[bh,t,d], K[bh,t,d], VT[bh,d,t] ----------------
__global__ __launch_bounds__(256)
void rearrange(const __bf16* __restrict__ qkv, __bf16* __restrict__ Q,
               __bf16* __restrict__ Kb, __bf16* __restrict__ VT)
{
  __shared__ __bf16 vt[64][72];
  const int tid = threadIdx.x;
  const int bid = blockIdx.x;
  const int bh = bid >> 5, tt = bid & 31;
  const int b = bh >> 4, h = bh & 15;
  const int t0 = tt * 64;
#pragma unroll
  for (int i = 0; i < 2; ++i) {
    const int c = i * 256 + tid;
    const int tk = c >> 3, d0 = (c & 7) * 8;
    const size_t srow = (size_t)(b * 2048 + t0 + tk) * 3072 + h * 64 + d0;
    const size_t drow = (size_t)(bh * 2048 + t0 + tk) * 64 + d0;
    *(bf16x8*)(Q + drow) = *(const bf16x8*)(qkv + srow);
    *(bf16x8*)(Kb + drow) = *(const bf16x8*)(qkv + srow + 1024);
    *(bf16x8*)&vt[tk][d0] = *(const bf16x8*)(qkv + srow + 2048);
  }
  __syncthreads();
#pragma unroll
  for (int i = 0; i < 2; ++i) {
    const int c = i * 256 + tid;
    const int d = c >> 3, s = (c & 7) * 8;
    bf16x8 o;
#pragma unroll
    for (int j = 0; j < 8; ++j) o[j] = vt[s + j][d];
    *(bf16x8*)(VT + (size_t)(bh * 64 + d) * 2048 + t0 + s) = o;
  }
}

// ---------------- flash attention, causal; 2 waves x 32 q-rows, KVBLK=64, 32x32x16 MFMA ----
// Swapped QK^T (S^T = K·Q^T) so each lane holds a lane-local P-row slice; softmax fully
// in-register; P->A-frag via v_cvt_pk_bf16_f32 + __builtin_amdgcn_permlane32_swap
// (returns {new_old, new_src}: new_old = {old.row0, src.row0}, new_src = {old.row1, src.row1}).
__global__ __launch_bounds__(128)
void attn(const __bf16* __restrict__ Q, const __bf16* __restrict__ K,
          const __bf16* __restrict__ VT, __bf16* __restrict__ O)
{
  const int bid = blockIdx.x;
  const int bh = bid >> 5, qt = 31 - (bid & 31);   // LPT: longest q-tiles first
  const int tid = threadIdx.x;
  const int lane = tid & 63, w = tid >> 6;
  const int l31 = lane & 31, hi = lane >> 5;
  __shared__ __bf16 Ks[64 * 64];
  __shared__ __bf16 Vs[64 * 64];
  const size_t base = (size_t)bh * 2048 * 64;
  const int qrow0 = qt * 64 + w * 32;
  const int xsw = (l31 & 7) << 3;

  bf16x8 qf[4];
#pragma unroll
  for (int s = 0; s < 4; ++s)
    qf[s] = *(const bf16x8*)(Q + base + (size_t)(qrow0 + l31) * 64 + s * 16 + hi * 8);

  f32x16 oa0 = {}, oa1 = {};
  float mst = -INFINITY, lst = 0.0f;

  for (int j = 0; j <= qt; ++j) {
#pragma unroll
    for (int rnd = 0; rnd < 4; ++rnd) {
      const int c = rnd * 128 + tid;
      const int r = c >> 3;
      const int e = ((c & 7) ^ (r & 7)) * 8;
      gll16(K + base + (size_t)(j * 64 + r) * 64 + e, Ks + c * 8);
      gll16(VT + base + (size_t)r * 2048 + j * 64 + e, Vs + c * 8);
    }
    __syncthreads();

    // S^T = K · Q^T : col(lane&31)=q, row(crow(reg,hi))=key
    f32x16 s0v = {}, s1v = {};
#pragma unroll
    for (int s = 0; s < 4; ++s) {
      const int co = (s * 16 + hi * 8) ^ xsw;
      bf16x8 ak0 = *(const bf16x8*)(Ks + l31 * 64 + co);
      bf16x8 ak1 = *(const bf16x8*)(Ks + (32 + l31) * 64 + co);
      s0v = __builtin_amdgcn_mfma_f32_32x32x16_bf16(ak0, qf[s], s0v, 0, 0, 0);
      s1v = __builtin_amdgcn_mfma_f32_32x32x16_bf16(ak1, qf[s], s1v, 0, 0, 0);
    }
#pragma unroll
    for (int rg = 0; rg < 16; ++rg) { s0v[rg] *= 0.125f; s1v[rg] *= 0.125f; }
    if (j == qt) {
      const int qg = qrow0 + l31;
#pragma unroll
      for (int rg = 0; rg < 16; ++rg) {
        const int kr = j * 64 + ((rg & 3) + 8 * (rg >> 2)) + 4 * hi;
        if (kr > qg) s0v[rg] = -INFINITY;
        if (kr + 32 > qg) s1v[rg] = -INFINITY;
      }
    }
    // in-register online softmax (row q=l31 split across lane & lane^32)
    float mx = s0v[0];
#pragma unroll
    for (int rg = 1; rg < 16; ++rg) mx = fmaxf(mx, s0v[rg]);
#pragma unroll
    for (int rg = 0; rg < 16; ++rg) mx = fmaxf(mx, s1v[rg]);
    mx = fmaxf(mx, __shfl_xor(mx, 32));
    const float mnew = fmaxf(mst, mx);
    const float cf = __expf(mst - mnew);
    float rs = 0.0f;
#pragma unroll
    for (int rg = 0; rg < 16; ++rg) {
      s0v[rg] = __expf(s0v[rg] - mnew); rs += s0v[rg];
      s1v[rg] = __expf(s1v[rg] - mnew); rs += s1v[rg];
    }
    rs += __shfl_xor(rs, 32);
    lst = lst * cf + rs;
    mst = mnew;
#pragma unroll
    for (int rg = 0; rg < 16; ++rg) {
      const float cb = __shfl(cf, (rg & 3) + 8 * (rg >> 2) + 4 * hi);
      oa0[rg] *= cb; oa1[rg] *= cb;
    }
    // P -> bf16 A-frags (cvt_pk + permlane32_swap), then O += P·V
#pragma unroll
    for (int s = 0; s < 4; ++s) {
      const int br = (s & 1) * 8;
      uint32_t wA0, wA1, wB0, wB1;
      if (s < 2) {
        asm("v_cvt_pk_bf16_f32 %0, %1, %2" : "=v"(wA0) : "v"(s0v[br + 0]), "v"(s0v[br + 1]));
        asm("v_cvt_pk_bf16_f32 %0, %1, %2" : "=v"(wA1) : "v"(s0v[br + 2]), "v"(s0v[br + 3]));
        asm("v_cvt_pk_bf16_f32 %0, %1, %2" : "=v"(wB0) : "v"(s0v[br + 4]), "v"(s0v[br + 5]));
        asm("v_cvt_pk_bf16_f32 %0, %1, %2" : "=v"(wB1) : "v"(s0v[br + 6]), "v"(s0v[br + 7]));
      } else {
        asm("v_cvt_pk_bf16_f32 %0, %1, %2" : "=v"(wA0) : "v"(s1v[br + 0]), "v"(s1v[br + 1]));
        asm("v_cvt_pk_bf16_f32 %0, %1, %2" : "=v"(wA1) : "v"(s1v[br + 2]), "v"(s1v[br + 3]));
        asm("v_cvt_pk_bf16_f32 %0, %1, %2" : "=v"(wB0) : "v"(s1v[br + 4]), "v"(s1v[br + 5]));
        asm("v_cvt_pk_bf16_f32 %0, %1, %2" : "=v"(wB1) : "v"(s1v[br + 6]), "v"(s1v[br + 7]));
      }
      const u32x2 r0 = __builtin_amdgcn_permlane32_swap(wA0, wB0, false, false);
      const u32x2 r1 = __builtin_amdgcn_permlane32_swap(wA1, wB1, false, false);
      u32x4 uu; uu.x = r0.x; uu.y = r1.x; uu.z = r0.y; uu.w = r1.y;
      const bf16x8 pa = __builtin_bit_cast(bf16x8, uu);
      const int co = (s * 16 + hi * 8) ^ xsw;
      bf16x8 bv0 = *(const bf16x8*)(Vs + l31 * 64 + co);
      bf16x8 bv1 = *(const bf16x8*)(Vs + (32 + l31) * 64 + co);
      oa0 = __builtin_amdgcn_mfma_f32_32x32x16_bf16(pa, bv0, oa0, 0, 0, 0);
      oa1 = __builtin_amdgcn_mfma_f32_32x32x16_bf16(pa, bv1, oa1, 0, 0, 0);
    }
    __syncthreads();
  }
  // epilogue: O[q][d], col(lane&31)=d, row(crow)=q
  const float inv = 1.0f / lst;
  const int b = bh >> 4, hd = bh & 15;
#pragma unroll
  for (int rg = 0; rg < 16; ++rg) {
    const int cr = (rg & 3) + 8 * (rg >> 2) + 4 * hi;
    const float ib = __shfl(inv, cr);
    const int qr = qrow0 + cr;
    O[(size_t)(b * 2048 + qr) * 1024 + hd * 64 + l31]      = (__bf16)(oa0[rg] * ib);
    O[(size_t)(b * 2048 + qr) * 1024 + hd * 64 + 32 + l31] = (__bf16)(oa1[rg] * ib);
  }
}

// ---------------- host ----------------
extern "C" void kernel_launch(void* const* d_in, const int* in_sizes, int n_in,
                              void* d_out, int out_size, void* d_ws, size_t ws_size,
                              hipStream_t stream)
{
  const float* x      = (const float*)d_in[0];
  const float* ln1_g  = (const float*)d_in[1];
  const float* ln1_b  = (const float*)d_in[2];
  const float* qkv_w  = (const float*)d_in[3];
  const float* qkv_b  = (const float*)d_in[4];
  const float* proj_w = (const float*)d_in[5];
  const float* proj_b = (const float*)d_in[6];
  const float* ln2_g  = (const float*)d_in[7];
  const float* ln2_b  = (const float*)d_in[8];
  const float* mlp_w1 = (const float*)d_in[9];
  const float* mlp_b1 = (const float*)d_in[10];
  const float* mlp_w2 = (const float*)d_in[11];
  const float* mlp_b2 = (const float*)d_in[12];

  char* ws = (char*)d_ws;
  __bf16* qkvT  = (__bf16*)(ws + 0);          //  6291456
  __bf16* projT = (__bf16*)(ws + 6291456);    //  2097152
  __bf16* w1T   = (__bf16*)(ws + 8388608);    //  8388608
  __bf16* w2T   = (__bf16*)(ws + 16777216);   //  8388608
  __bf16* h1    = (__bf16*)(ws + 25165824);   //  8388608
  __bf16* qkv   = (__bf16*)(ws + 33554432);   // 25165824 (dead after rearrange)
  __bf16* act1  = (__bf16*)(ws + 33554432);   // 33554432, aliases qkv+Qb (both dead by MLP1)
  __bf16* Qb    = (__bf16*)(ws + 58720256);   //  8388608
  __bf16* Kb    = (__bf16*)(ws + 67108864);   //  8388608
  __bf16* VTb   = (__bf16*)(ws + 75497472);   //  8388608
  __bf16* attO  = (__bf16*)(ws + 83886080);   //  8388608
  float*  x2    = (float*) (ws + 92274688);   // 16777216
  __bf16* h2    = (__bf16*)(ws + 109051904);  //  8388608  (total 117440512 B)

  convT<<<dim3(48, 16), 256, 0, stream>>>(qkv_w, qkvT, 1024, 3072);
  convT<<<dim3(16, 16), 256, 0, stream>>>(proj_w, projT, 1024, 1024);
  convT<<<dim3(64, 16), 256, 0, stream>>>(mlp_w1, w1T, 1024, 4096);
  convT<<<dim3(16, 64), 256, 0, stream>>>(mlp_w2, w2T, 4096, 1024);

  ln_rows<<<4096, 256, 0, stream>>>(x, ln1_g, ln1_b, h1);
  gemm_bt<EPI_BF16><<<dim3(24, 32), 256, 0, stream>>>(h1, qkvT, qkv_b, nullptr, qkv, 4096, 3072, 1024);
  rearrange<<<1024, 256, 0, stream>>>(qkv, Qb, Kb, VTb);
  attn<<<1024, 128, 0, stream>>>(Qb, Kb, VTb, attO);
  gemm_bt<EPI_RES><<<dim3(8, 32), 256, 0, stream>>>(attO, projT, proj_b, x, x2, 4096, 1024, 1024);
  ln_rows<<<4096, 256, 0, stream>>>(x2, ln2_g, ln2_b, h2);
  gemm_bt<EPI_GELU><<<dim3(32, 32), 256, 0, stream>>>(h2, w1T, mlp_b1, nullptr, act1, 4096, 4096, 1024);
  gemm_bt<EPI_RES><<<dim3(8, 32), 256, 0, stream>>>(act1, w2T, mlp_b2, x2, (float*)d_out, 4096, 1024, 4096);
}

// Round 5
// 417.642 us; speedup vs baseline: 1.2997x; 1.0621x over previous
//
#include <hip/hip_runtime.h>
#include <hip/hip_bf16.h>
#include <cstdint>

typedef __attribute__((ext_vector_type(4))) float f32x4;
typedef __attribute__((ext_vector_type(16))) float f32x16;
typedef __attribute__((ext_vector_type(8))) __bf16 bf16x8;
typedef __attribute__((ext_vector_type(4))) __bf16 bf16x4;
typedef __attribute__((ext_vector_type(4))) uint32_t u32x4;
typedef __attribute__((ext_vector_type(2))) unsigned int u32x2;

#define EPI_BF16 0
#define EPI_GELU 1
#define EPI_RES  2
#define EPI_PART 3

__device__ __forceinline__ void gll16(const void* g, void* l) {
  __builtin_amdgcn_global_load_lds((__attribute__((address_space(1))) void*)(g),
                                   (__attribute__((address_space(3))) void*)(l), 16, 0, 0);
}

// ---------------- weight convert + transpose: W[K,N] fp32 -> WT[N,K] bf16 ----------------
__global__ __launch_bounds__(256)
void convT(const float* __restrict__ W, __bf16* __restrict__ WT, int Kd, int Nd)
{
  __shared__ __bf16 t[64][72];
  const int tid = threadIdx.x;
  const int n0 = blockIdx.x * 64, k0 = blockIdx.y * 64;
#pragma unroll
  for (int i = 0; i < 4; ++i) {
    const int c = i * 256 + tid;
    const int r = c >> 4, cc = (c & 15) * 4;
    const float4 v = *(const float4*)(W + (size_t)(k0 + r) * Nd + n0 + cc);
    bf16x4 tv; tv[0] = (__bf16)v.x; tv[1] = (__bf16)v.y; tv[2] = (__bf16)v.z; tv[3] = (__bf16)v.w;
    *(bf16x4*)&t[r][cc] = tv;
  }
  __syncthreads();
#pragma unroll
  for (int i = 0; i < 2; ++i) {
    const int c = i * 256 + tid;
    const int n = c >> 3, s = (c & 7) * 8;
    bf16x8 o;
#pragma unroll
    for (int j = 0; j < 8; ++j) o[j] = t[s + j][n];
    *(bf16x8*)(WT + (size_t)(n0 + n) * Kd + k0 + s) = o;
  }
}

// ---------------- LayerNorm rows of 1024, fp32 in -> bf16 out ----------------
__global__ __launch_bounds__(256)
void ln_rows(const float* __restrict__ x, const float* __restrict__ g,
             const float* __restrict__ b, __bf16* __restrict__ out)
{
  const int row = blockIdx.x;
  const int tid = threadIdx.x;
  const float4 v = *(const float4*)(x + (size_t)row * 1024 + tid * 4);
  float s = v.x + v.y + v.z + v.w;
  float q = v.x * v.x + v.y * v.y + v.z * v.z + v.w * v.w;
#pragma unroll
  for (int o = 32; o; o >>= 1) { s += __shfl_xor(s, o); q += __shfl_xor(q, o); }
  __shared__ float red[8];
  const int wid = tid >> 6;
  if ((tid & 63) == 0) { red[wid] = s; red[4 + wid] = q; }
  __syncthreads();
  s = red[0] + red[1] + red[2] + red[3];
  q = red[4] + red[5] + red[6] + red[7];
  const float mu = s * (1.0f / 1024.0f);
  const float var = q * (1.0f / 1024.0f) - mu * mu;
  const float rs = rsqrtf(var + 1e-5f);
  bf16x4 o4;
#pragma unroll
  for (int i = 0; i < 4; ++i) {
    const int c = tid * 4 + i;
    const float xv = (&v.x)[i];
    o4[i] = (__bf16)((xv - mu) * rs * g[c] + b[c]);
  }
  *(bf16x4*)(out + (size_t)row * 1024 + tid * 4) = o4;
}

// ---------------- GEMM: C[M,N] = A[M,K](bf16) * W, W given as WT[N,K](bf16) ----------------
// LDS XOR-swizzled (pre-swizzled global source + matching read XOR) -> conflict-free b128.
// XCD-aware block swizzle: consecutive logical tiles (same A-panel) on one XCD.
// EPI_PART: split-K partial (gridDim.z slices), raw fp32 acc to P[z][M][N], no bias.
template<int EPI>
__global__ __launch_bounds__(256)
void gemm_bt(const __bf16* __restrict__ A, const __bf16* __restrict__ BT,
             const float* __restrict__ bias, const float* __restrict__ R,
             void* __restrict__ Out, int M, int N, int K)
{
  const int tid = threadIdx.x;
  const int lane = tid & 63, wid = tid >> 6;
  const int l15 = lane & 15, lg = lane >> 4;
  const int wm = (wid >> 1) * 64, wn = (wid & 1) * 64;
  // XCD swizzle (nwg multiple of 8 for all launches)
  const int nwg = gridDim.x * gridDim.y;
  const int hw = blockIdx.y * gridDim.x + blockIdx.x;
  const int logical = (hw & 7) * (nwg >> 3) + (hw >> 3);
  const int rowBase = (logical / gridDim.x) * 128;
  const int colBase = (logical % gridDim.x) * 128;
  const int kLen = K / gridDim.z;
  const int kBeg = blockIdx.z * kLen;
  __shared__ __bf16 As[128 * 32];
  __shared__ __bf16 Bs[128 * 32];
  f32x4 acc[4][4] = {};
  const int fsw = ((l15 >> 1) & 3) << 3;   // frag-read element XOR

  for (int k0 = kBeg; k0 < kBeg + kLen; k0 += 32) {
#pragma unroll
    for (int i = 0; i < 2; ++i) {
      const int c = i * 256 + tid;
      const int r = c >> 2;
      const int s = ((c & 3) ^ ((r >> 1) & 3)) * 8;   // pre-swizzled global chunk
      gll16(A + (size_t)(rowBase + r) * K + (k0 + s), As + c * 8);
    }
#pragma unroll
    for (int i = 0; i < 2; ++i) {
      const int c = i * 256 + tid;
      const int r = c >> 2;
      const int s = ((c & 3) ^ ((r >> 1) & 3)) * 8;
      gll16(BT + (size_t)(colBase + r) * K + (k0 + s), Bs + c * 8);
    }
    __syncthreads();
    bf16x8 af[4], bfr[4];
#pragma unroll
    for (int m = 0; m < 4; ++m) af[m] = *(const bf16x8*)(As + (wm + m * 16 + l15) * 32 + (lg * 8 ^ fsw));
#pragma unroll
    for (int n = 0; n < 4; ++n) bfr[n] = *(const bf16x8*)(Bs + (wn + n * 16 + l15) * 32 + (lg * 8 ^ fsw));
#pragma unroll
    for (int m = 0; m < 4; ++m)
#pragma unroll
      for (int n = 0; n < 4; ++n)
        acc[m][n] = __builtin_amdgcn_mfma_f32_16x16x32_bf16(af[m], bfr[n], acc[m][n], 0, 0, 0);
    __syncthreads();
  }
#pragma unroll
  for (int m = 0; m < 4; ++m) {
#pragma unroll
    for (int n = 0; n < 4; ++n) {
      const int col = colBase + wn + n * 16 + l15;
      float bb = 0.0f;
      if constexpr (EPI != EPI_PART) bb = bias[col];
#pragma unroll
      for (int i = 0; i < 4; ++i) {
        const int row = rowBase + wm + m * 16 + lg * 4 + i;
        float v = acc[m][n][i] + bb;
        if constexpr (EPI == EPI_GELU) {
          v = 0.5f * v * (1.0f + erff(v * 0.70710678118654752f));
          ((__bf16*)Out)[(size_t)row * N + col] = (__bf16)v;
        } else if constexpr (EPI == EPI_BF16) {
          ((__bf16*)Out)[(size_t)row * N + col] = (__bf16)v;
        } else if constexpr (EPI == EPI_RES) {
          v += R[(size_t)row * N + col];
          ((float*)Out)[(size_t)row * N + col] = v;
        } else {
          ((float*)Out)[((size_t)blockIdx.z * M + row) * N + col] = v;
        }
      }
    }
  }
}

// ---------------- split-K reduce: out = P0 + P1 + bias + R ----------------
__global__ __launch_bounds__(256)
void reduce2(const float* __restrict__ P, const float* __restrict__ bias,
             const float* __restrict__ R, float* __restrict__ Out, int MN, int N)
{
  const size_t e = ((size_t)blockIdx.x * 256 + threadIdx.x) * 4;
  const float4 a = *(const float4*)(P + e);
  const float4 b = *(const float4*)(P + (size_t)MN + e);
  const float4 r = *(const float4*)(R + e);
  const float4 bb = *(const float4*)(bias + (e & (size_t)(N - 1)));
  float4 o;
  o.x = a.x + b.x + r.x + bb.x;
  o.y = a.y + b.y + r.y + bb.y;
  o.z = a.z + b.z + r.z + bb.z;
  o.w = a.w + b.w + r.w + bb.w;
  *(float4*)(Out + e) = o;
}

// ---------------- rearrange qkv[4096,3072] -> Q[bh,t,d], K[bh,t,d], VT[bh,d,t] ----------------
__global__ __launch_bounds__(256)
void rearrange(const __bf16* __restrict__ qkv, __bf16* __restrict__ Q,
               __bf16* __restrict__ Kb, __bf16* __restrict__ VT)
{
  __shared__ __bf16 vt[64][72];
  const int tid = threadIdx.x;
  const int bid = blockIdx.x;
  const int bh = bid >> 5, tt = bid & 31;
  const int b = bh >> 4, h = bh & 15;
  const int t0 = tt * 64;
#pragma unroll
  for (int i = 0; i < 2; ++i) {
    const int c = i * 256 + tid;
    const int tk = c >> 3, d0 = (c & 7) * 8;
    const size_t srow = (size_t)(b * 2048 + t0 + tk) * 3072 + h * 64 + d0;
    const size_t drow = (size_t)(bh * 2048 + t0 + tk) * 64 + d0;
    *(bf16x8*)(Q + drow) = *(const bf16x8*)(qkv + srow);
    *(bf16x8*)(Kb + drow) = *(const bf16x8*)(qkv + srow + 1024);
    *(bf16x8*)&vt[tk][d0] = *(const bf16x8*)(qkv + srow + 2048);
  }
  __syncthreads();
#pragma unroll
  for (int i = 0; i < 2; ++i) {
    const int c = i * 256 + tid;
    const int d = c >> 3, s = (c & 7) * 8;
    bf16x8 o;
#pragma unroll
    for (int j = 0; j < 8; ++j) o[j] = vt[s + j][d];
    *(bf16x8*)(VT + (size_t)(bh * 64 + d) * 2048 + t0 + s) = o;
  }
}

// ---------------- flash attention, causal; 2 waves x 32 q-rows, KVBLK=64, 32x32x16 MFMA ----
__global__ __launch_bounds__(128)
void attn(const __bf16* __restrict__ Q, const __bf16* __restrict__ K,
          const __bf16* __restrict__ VT, __bf16* __restrict__ O)
{
  const int bid = blockIdx.x;
  const int bh = bid >> 5, qt = 31 - (bid & 31);   // LPT: longest q-tiles first
  const int tid = threadIdx.x;
  const int lane = tid & 63, w = tid >> 6;
  const int l31 = lane & 31, hi = lane >> 5;
  __shared__ __bf16 Ks[64 * 64];
  __shared__ __bf16 Vs[64 * 64];
  const size_t base = (size_t)bh * 2048 * 64;
  const int qrow0 = qt * 64 + w * 32;
  const int xsw = (l31 & 7) << 3;

  bf16x8 qf[4];
#pragma unroll
  for (int s = 0; s < 4; ++s)
    qf[s] = *(const bf16x8*)(Q + base + (size_t)(qrow0 + l31) * 64 + s * 16 + hi * 8);

  f32x16 oa0 = {}, oa1 = {};
  float mst = -INFINITY, lst = 0.0f;

  for (int j = 0; j <= qt; ++j) {
#pragma unroll
    for (int rnd = 0; rnd < 4; ++rnd) {
      const int c = rnd * 128 + tid;
      const int r = c >> 3;
      const int e = ((c & 7) ^ (r & 7)) * 8;
      gll16(K + base + (size_t)(j * 64 + r) * 64 + e, Ks + c * 8);
      gll16(VT + base + (size_t)r * 2048 + j * 64 + e, Vs + c * 8);
    }
    __syncthreads();

    f32x16 s0v = {}, s1v = {};
#pragma unroll
    for (int s = 0; s < 4; ++s) {
      const int co = (s * 16 + hi * 8) ^ xsw;
      bf16x8 ak0 = *(const bf16x8*)(Ks + l31 * 64 + co);
      bf16x8 ak1 = *(const bf16x8*)(Ks + (32 + l31) * 64 + co);
      s0v = __builtin_amdgcn_mfma_f32_32x32x16_bf16(ak0, qf[s], s0v, 0, 0, 0);
      s1v = __builtin_amdgcn_mfma_f32_32x32x16_bf16(ak1, qf[s], s1v, 0, 0, 0);
    }
#pragma unroll
    for (int rg = 0; rg < 16; ++rg) { s0v[rg] *= 0.125f; s1v[rg] *= 0.125f; }
    if (j == qt) {
      const int qg = qrow0 + l31;
#pragma unroll
      for (int rg = 0; rg < 16; ++rg) {
        const int kr = j * 64 + ((rg & 3) + 8 * (rg >> 2)) + 4 * hi;
        if (kr > qg) s0v[rg] = -INFINITY;
        if (kr + 32 > qg) s1v[rg] = -INFINITY;
      }
    }
    float mx = s0v[0];
#pragma unroll
    for (int rg = 1; rg < 16; ++rg) mx = fmaxf(mx, s0v[rg]);
#pragma unroll
    for (int rg = 0; rg < 16; ++rg) mx = fmaxf(mx, s1v[rg]);
    mx = fmaxf(mx, __shfl_xor(mx, 32));
    const float mnew = fmaxf(mst, mx);
    const float cf = __expf(mst - mnew);
    float rs = 0.0f;
#pragma unroll
    for (int rg = 0; rg < 16; ++rg) {
      s0v[rg] = __expf(s0v[rg] - mnew); rs += s0v[rg];
      s1v[rg] = __expf(s1v[rg] - mnew); rs += s1v[rg];
    }
    rs += __shfl_xor(rs, 32);
    lst = lst * cf + rs;
    mst = mnew;
#pragma unroll
    for (int rg = 0; rg < 16; ++rg) {
      const float cb = __shfl(cf, (rg & 3) + 8 * (rg >> 2) + 4 * hi);
      oa0[rg] *= cb; oa1[rg] *= cb;
    }
#pragma unroll
    for (int s = 0; s < 4; ++s) {
      const int br = (s & 1) * 8;
      uint32_t wA0, wA1, wB0, wB1;
      if (s < 2) {
        asm("v_cvt_pk_bf16_f32 %0, %1, %2" : "=v"(wA0) : "v"(s0v[br + 0]), "v"(s0v[br + 1]));
        asm("v_cvt_pk_bf16_f32 %0, %1, %2" : "=v"(wA1) : "v"(s0v[br + 2]), "v"(s0v[br + 3]));
        asm("v_cvt_pk_bf16_f32 %0, %1, %2" : "=v"(wB0) : "v"(s0v[br + 4]), "v"(s0v[br + 5]));
        asm("v_cvt_pk_bf16_f32 %0, %1, %2" : "=v"(wB1) : "v"(s0v[br + 6]), "v"(s0v[br + 7]));
      } else {
        asm("v_cvt_pk_bf16_f32 %0, %1, %2" : "=v"(wA0) : "v"(s1v[br + 0]), "v"(s1v[br + 1]));
        asm("v_cvt_pk_bf16_f32 %0, %1, %2" : "=v"(wA1) : "v"(s1v[br + 2]), "v"(s1v[br + 3]));
        asm("v_cvt_pk_bf16_f32 %0, %1, %2" : "=v"(wB0) : "v"(s1v[br + 4]), "v"(s1v[br + 5]));
        asm("v_cvt_pk_bf16_f32 %0, %1, %2" : "=v"(wB1) : "v"(s1v[br + 6]), "v"(s1v[br + 7]));
      }
      const u32x2 r0 = __builtin_amdgcn_permlane32_swap(wA0, wB0, false, false);
      const u32x2 r1 = __builtin_amdgcn_permlane32_swap(wA1, wB1, false, false);
      u32x4 uu; uu.x = r0.x; uu.y = r1.x; uu.z = r0.y; uu.w = r1.y;
      const bf16x8 pa = __builtin_bit_cast(bf16x8, uu);
      const int co = (s * 16 + hi * 8) ^ xsw;
      bf16x8 bv0 = *(const bf16x8*)(Vs + l31 * 64 + co);
      bf16x8 bv1 = *(const bf16x8*)(Vs + (32 + l31) * 64 + co);
      oa0 = __builtin_amdgcn_mfma_f32_32x32x16_bf16(pa, bv0, oa0, 0, 0, 0);
      oa1 = __builtin_amdgcn_mfma_f32_32x32x16_bf16(pa, bv1, oa1, 0, 0, 0);
    }
    __syncthreads();
  }
  const float inv = 1.0f / lst;
  const int b = bh >> 4, hd = bh & 15;
#pragma unroll
  for (int rg = 0; rg < 16; ++rg) {
    const int cr = (rg & 3) + 8 * (rg >> 2) + 4 * hi;
    const float ib = __shfl(inv, cr);
    const int qr = qrow0 + cr;
    O[(size_t)(b * 2048 + qr) * 1024 + hd * 64 + l31]      = (__bf16)(oa0[rg] * ib);
    O[(size_t)(b * 2048 + qr) * 1024 + hd * 64 + 32 + l31] = (__bf16)(oa1[rg] * ib);
  }
}

// ---------------- host ----------------
extern "C" void kernel_launch(void* const* d_in, const int* in_sizes, int n_in,
                              void* d_out, int out_size, void* d_ws, size_t ws_size,
                              hipStream_t stream)
{
  const float* x      = (const float*)d_in[0];
  const float* ln1_g  = (const float*)d_in[1];
  const float* ln1_b  = (const float*)d_in[2];
  const float* qkv_w  = (const float*)d_in[3];
  const float* qkv_b  = (const float*)d_in[4];
  const float* proj_w = (const float*)d_in[5];
  const float* proj_b = (const float*)d_in[6];
  const float* ln2_g  = (const float*)d_in[7];
  const float* ln2_b  = (const float*)d_in[8];
  const float* mlp_w1 = (const float*)d_in[9];
  const float* mlp_b1 = (const float*)d_in[10];
  const float* mlp_w2 = (const float*)d_in[11];
  const float* mlp_b2 = (const float*)d_in[12];

  // Workspace layout (liveness-packed, 109051904 B total):
  //   [0, 25165824)            weights: qkvT, projT, w1T, w2T        (persistent)
  //   [25165824, 41943040)     x2 fp32                               (proj -> reduce2)
  //   [41943040, 75497472)     act1 32MB (mlp1 -> mlp2)  | aliases: h1 8MB, qkv 25MB @50331648
  //   [75497472, 109051904)    part 33.5MB (mlp2 -> red) | aliases: Qb/Kb/VTb 24MB, attO 8MB @100663296, h2 8MB @75497472
  char* ws = (char*)d_ws;
  __bf16* qkvT  = (__bf16*)(ws + 0);
  __bf16* projT = (__bf16*)(ws + 6291456);
  __bf16* w1T   = (__bf16*)(ws + 8388608);
  __bf16* w2T   = (__bf16*)(ws + 16777216);
  float*  x2    = (float*) (ws + 25165824);
  __bf16* act1  = (__bf16*)(ws + 41943040);
  __bf16* h1    = (__bf16*)(ws + 41943040);
  __bf16* qkv   = (__bf16*)(ws + 50331648);
  float*  part  = (float*) (ws + 75497472);
  __bf16* h2    = (__bf16*)(ws + 75497472);
  __bf16* Qb    = (__bf16*)(ws + 75497472);
  __bf16* Kb    = (__bf16*)(ws + 83886080);
  __bf16* VTb   = (__bf16*)(ws + 92274688);
  __bf16* attO  = (__bf16*)(ws + 100663296);

  convT<<<dim3(48, 16), 256, 0, stream>>>(qkv_w, qkvT, 1024, 3072);
  convT<<<dim3(16, 16), 256, 0, stream>>>(proj_w, projT, 1024, 1024);
  convT<<<dim3(64, 16), 256, 0, stream>>>(mlp_w1, w1T, 1024, 4096);
  convT<<<dim3(16, 64), 256, 0, stream>>>(mlp_w2, w2T, 4096, 1024);

  ln_rows<<<4096, 256, 0, stream>>>(x, ln1_g, ln1_b, h1);
  gemm_bt<EPI_BF16><<<dim3(24, 32), 256, 0, stream>>>(h1, qkvT, qkv_b, nullptr, qkv, 4096, 3072, 1024);
  rearrange<<<1024, 256, 0, stream>>>(qkv, Qb, Kb, VTb);
  attn<<<1024, 128, 0, stream>>>(Qb, Kb, VTb, attO);
  gemm_bt<EPI_RES><<<dim3(8, 32), 256, 0, stream>>>(attO, projT, proj_b, x, x2, 4096, 1024, 1024);
  ln_rows<<<4096, 256, 0, stream>>>(x2, ln2_g, ln2_b, h2);
  gemm_bt<EPI_GELU><<<dim3(32, 32), 256, 0, stream>>>(h2, w1T, mlp_b1, nullptr, act1, 4096, 4096, 1024);
  gemm_bt<EPI_PART><<<dim3(8, 32, 2), 256, 0, stream>>>(act1, w2T, nullptr, nullptr, part, 4096, 1024, 4096);
  reduce2<<<4096, 256, 0, stream>>>(part, mlp_b2, x2, (float*)d_out, 4096 * 1024, 1024);
}

// Round 6
// 414.923 us; speedup vs baseline: 1.3082x; 1.0066x over previous
//
#include <hip/hip_runtime.h>
#include <hip/hip_bf16.h>
#include <cstdint>

typedef __attribute__((ext_vector_type(4))) float f32x4;
typedef __attribute__((ext_vector_type(16))) float f32x16;
typedef __attribute__((ext_vector_type(8))) __bf16 bf16x8;
typedef __attribute__((ext_vector_type(4))) __bf16 bf16x4;
typedef __attribute__((ext_vector_type(4))) uint32_t u32x4;
typedef __attribute__((ext_vector_type(2))) unsigned int u32x2;

#define EPI_BF16  0
#define EPI_GELU  1
#define EPI_RES   2
#define EPI_PART  3
#define EPI_PARTB 4

__device__ __forceinline__ void gll16(const void* g, void* l) {
  __builtin_amdgcn_global_load_lds((__attribute__((address_space(1))) void*)(g),
                                   (__attribute__((address_space(3))) void*)(l), 16, 0, 0);
}

// ---------------- weight convert+transpose, all 4 weights in one launch ----------------
__global__ __launch_bounds__(256)
void convT_all(const float* __restrict__ W0, __bf16* __restrict__ T0,
               const float* __restrict__ W1, __bf16* __restrict__ T1,
               const float* __restrict__ W2, __bf16* __restrict__ T2,
               const float* __restrict__ W3, __bf16* __restrict__ T3)
{
  __shared__ __bf16 t[64][72];
  const int bid = blockIdx.x;
  const float* W; __bf16* WT; int Kd, Nd, nx, lb;
  if (bid < 768)       { W = W0; WT = T0; Kd = 1024; Nd = 3072; nx = 48; lb = bid; }
  else if (bid < 1024) { W = W1; WT = T1; Kd = 1024; Nd = 1024; nx = 16; lb = bid - 768; }
  else if (bid < 2048) { W = W2; WT = T2; Kd = 1024; Nd = 4096; nx = 64; lb = bid - 1024; }
  else                 { W = W3; WT = T3; Kd = 4096; Nd = 1024; nx = 16; lb = bid - 2048; }
  const int tid = threadIdx.x;
  const int n0 = (lb % nx) * 64, k0 = (lb / nx) * 64;
#pragma unroll
  for (int i = 0; i < 4; ++i) {
    const int c = i * 256 + tid;
    const int r = c >> 4, cc = (c & 15) * 4;
    const float4 v = *(const float4*)(W + (size_t)(k0 + r) * Nd + n0 + cc);
    bf16x4 tv; tv[0] = (__bf16)v.x; tv[1] = (__bf16)v.y; tv[2] = (__bf16)v.z; tv[3] = (__bf16)v.w;
    *(bf16x4*)&t[r][cc] = tv;
  }
  __syncthreads();
#pragma unroll
  for (int i = 0; i < 2; ++i) {
    const int c = i * 256 + tid;
    const int n = c >> 3, s = (c & 7) * 8;
    bf16x8 o;
#pragma unroll
    for (int j = 0; j < 8; ++j) o[j] = t[s + j][n];
    *(bf16x8*)(WT + (size_t)(n0 + n) * Kd + k0 + s) = o;
  }
}

// ---------------- LayerNorm rows of 1024, fp32 in -> bf16 out ----------------
__global__ __launch_bounds__(256)
void ln_rows(const float* __restrict__ x, const float* __restrict__ g,
             const float* __restrict__ b, __bf16* __restrict__ out)
{
  const int row = blockIdx.x;
  const int tid = threadIdx.x;
  const float4 v = *(const float4*)(x + (size_t)row * 1024 + tid * 4);
  float s = v.x + v.y + v.z + v.w;
  float q = v.x * v.x + v.y * v.y + v.z * v.z + v.w * v.w;
#pragma unroll
  for (int o = 32; o; o >>= 1) { s += __shfl_xor(s, o); q += __shfl_xor(q, o); }
  __shared__ float red[8];
  const int wid = tid >> 6;
  if ((tid & 63) == 0) { red[wid] = s; red[4 + wid] = q; }
  __syncthreads();
  s = red[0] + red[1] + red[2] + red[3];
  q = red[4] + red[5] + red[6] + red[7];
  const float mu = s * (1.0f / 1024.0f);
  const float var = q * (1.0f / 1024.0f) - mu * mu;
  const float rs = rsqrtf(var + 1e-5f);
  bf16x4 o4;
#pragma unroll
  for (int i = 0; i < 4; ++i) {
    const int c = tid * 4 + i;
    const float xv = (&v.x)[i];
    o4[i] = (__bf16)((xv - mu) * rs * g[c] + b[c]);
  }
  *(bf16x4*)(out + (size_t)row * 1024 + tid * 4) = o4;
}

// ---------------- GEMM: C[M,N] = A[M,K](bf16) * W, W given as WT[N,K](bf16) ----------------
// Conflict-free LDS via pre-swizzled global source + matching read XOR. XCD block swizzle.
// EPI_PART/PARTB: split-K partials (fp32 / bf16) to P[z][M][N], no bias.
template<int EPI>
__global__ __launch_bounds__(256)
void gemm_bt(const __bf16* __restrict__ A, const __bf16* __restrict__ BT,
             const float* __restrict__ bias, const float* __restrict__ R,
             void* __restrict__ Out, int M, int N, int K)
{
  const int tid = threadIdx.x;
  const int lane = tid & 63, wid = tid >> 6;
  const int l15 = lane & 15, lg = lane >> 4;
  const int wm = (wid >> 1) * 64, wn = (wid & 1) * 64;
  const int nwg = gridDim.x * gridDim.y;
  const int hw = blockIdx.y * gridDim.x + blockIdx.x;
  const int logical = (hw & 7) * (nwg >> 3) + (hw >> 3);
  const int rowBase = (logical / gridDim.x) * 128;
  const int colBase = (logical % gridDim.x) * 128;
  const int kLen = K / gridDim.z;
  const int kBeg = blockIdx.z * kLen;
  __shared__ __bf16 As[128 * 32];
  __shared__ __bf16 Bs[128 * 32];
  f32x4 acc[4][4] = {};
  const int fsw = ((l15 >> 1) & 3) << 3;

  for (int k0 = kBeg; k0 < kBeg + kLen; k0 += 32) {
#pragma unroll
    for (int i = 0; i < 2; ++i) {
      const int c = i * 256 + tid;
      const int r = c >> 2;
      const int s = ((c & 3) ^ ((r >> 1) & 3)) * 8;
      gll16(A + (size_t)(rowBase + r) * K + (k0 + s), As + c * 8);
    }
#pragma unroll
    for (int i = 0; i < 2; ++i) {
      const int c = i * 256 + tid;
      const int r = c >> 2;
      const int s = ((c & 3) ^ ((r >> 1) & 3)) * 8;
      gll16(BT + (size_t)(colBase + r) * K + (k0 + s), Bs + c * 8);
    }
    __syncthreads();
    bf16x8 af[4], bfr[4];
#pragma unroll
    for (int m = 0; m < 4; ++m) af[m] = *(const bf16x8*)(As + (wm + m * 16 + l15) * 32 + (lg * 8 ^ fsw));
#pragma unroll
    for (int n = 0; n < 4; ++n) bfr[n] = *(const bf16x8*)(Bs + (wn + n * 16 + l15) * 32 + (lg * 8 ^ fsw));
#pragma unroll
    for (int m = 0; m < 4; ++m)
#pragma unroll
      for (int n = 0; n < 4; ++n)
        acc[m][n] = __builtin_amdgcn_mfma_f32_16x16x32_bf16(af[m], bfr[n], acc[m][n], 0, 0, 0);
    __syncthreads();
  }
#pragma unroll
  for (int m = 0; m < 4; ++m) {
#pragma unroll
    for (int n = 0; n < 4; ++n) {
      const int col = colBase + wn + n * 16 + l15;
      float bb = 0.0f;
      if constexpr (EPI != EPI_PART && EPI != EPI_PARTB) bb = bias[col];
#pragma unroll
      for (int i = 0; i < 4; ++i) {
        const int row = rowBase + wm + m * 16 + lg * 4 + i;
        float v = acc[m][n][i] + bb;
        if constexpr (EPI == EPI_GELU) {
          v = 0.5f * v * (1.0f + erff(v * 0.70710678118654752f));
          ((__bf16*)Out)[(size_t)row * N + col] = (__bf16)v;
        } else if constexpr (EPI == EPI_BF16) {
          ((__bf16*)Out)[(size_t)row * N + col] = (__bf16)v;
        } else if constexpr (EPI == EPI_RES) {
          v += R[(size_t)row * N + col];
          ((float*)Out)[(size_t)row * N + col] = v;
        } else if constexpr (EPI == EPI_PART) {
          ((float*)Out)[((size_t)blockIdx.z * M + row) * N + col] = v;
        } else {
          ((__bf16*)Out)[((size_t)blockIdx.z * M + row) * N + col] = (__bf16)v;
        }
      }
    }
  }
}

// ---------------- split-K reduce (2 fp32 partials): out = P0+P1+bias+R ----------------
__global__ __launch_bounds__(256)
void reduce2(const float* __restrict__ P, const float* __restrict__ bias,
             const float* __restrict__ R, float* __restrict__ Out, int MN, int N)
{
  const size_t e = ((size_t)blockIdx.x * 256 + threadIdx.x) * 4;
  const float4 a = *(const float4*)(P + e);
  const float4 b = *(const float4*)(P + (size_t)MN + e);
  const float4 r = *(const float4*)(R + e);
  const float4 bb = *(const float4*)(bias + (e & (size_t)(N - 1)));
  float4 o;
  o.x = a.x + b.x + r.x + bb.x;
  o.y = a.y + b.y + r.y + bb.y;
  o.z = a.z + b.z + r.z + bb.z;
  o.w = a.w + b.w + r.w + bb.w;
  *(float4*)(Out + e) = o;
}

// ---------------- split-K reduce (4 bf16 partials): out = sum P + bias + R ----------------
__global__ __launch_bounds__(256)
void reduce4(const __bf16* __restrict__ P, const float* __restrict__ bias,
             const float* __restrict__ R, float* __restrict__ Out, int MN, int N)
{
  const size_t e = ((size_t)blockIdx.x * 256 + threadIdx.x) * 8;
  float s[8];
#pragma unroll
  for (int i = 0; i < 8; ++i) s[i] = 0.0f;
#pragma unroll
  for (int p = 0; p < 4; ++p) {
    const bf16x8 v = *(const bf16x8*)(P + (size_t)p * MN + e);
#pragma unroll
    for (int i = 0; i < 8; ++i) s[i] += (float)v[i];
  }
  const size_t col = e & (size_t)(N - 1);
  const float4 r0 = *(const float4*)(R + e),       r1 = *(const float4*)(R + e + 4);
  const float4 b0 = *(const float4*)(bias + col),  b1 = *(const float4*)(bias + col + 4);
  float4 o0, o1;
  o0.x = s[0] + r0.x + b0.x; o0.y = s[1] + r0.y + b0.y;
  o0.z = s[2] + r0.z + b0.z; o0.w = s[3] + r0.w + b0.w;
  o1.x = s[4] + r1.x + b1.x; o1.y = s[5] + r1.y + b1.y;
  o1.z = s[6] + r1.z + b1.z; o1.w = s[7] + r1.w + b1.w;
  *(float4*)(Out + e)     = o0;
  *(float4*)(Out + e + 4) = o1;
}

// ---------------- rearrange qkv[4096,3072] -> Q[bh,t,d], K[bh,t,d], VT[bh,d,t] ----------------
__global__ __launch_bounds__(256)
void rearrange(const __bf16* __restrict__ qkv, __bf16* __restrict__ Q,
               __bf16* __restrict__ Kb, __bf16* __restrict__ VT)
{
  __shared__ __bf16 vt[64][72];
  const int tid = threadIdx.x;
  const int bid = blockIdx.x;
  const int bh = bid >> 5, tt = bid & 31;
  const int b = bh >> 4, h = bh & 15;
  const int t0 = tt * 64;
#pragma unroll
  for (int i = 0; i < 2; ++i) {
    const int c = i * 256 + tid;
    const int tk = c >> 3, d0 = (c & 7) * 8;
    const size_t srow = (size_t)(b * 2048 + t0 + tk) * 3072 + h * 64 + d0;
    const size_t drow = (size_t)(bh * 2048 + t0 + tk) * 64 + d0;
    *(bf16x8*)(Q + drow) = *(const bf16x8*)(qkv + srow);
    *(bf16x8*)(Kb + drow) = *(const bf16x8*)(qkv + srow + 1024);
    *(bf16x8*)&vt[tk][d0] = *(const bf16x8*)(qkv + srow + 2048);
  }
  __syncthreads();
#pragma unroll
  for (int i = 0; i < 2; ++i) {
    const int c = i * 256 + tid;
    const int d = c >> 3, s = (c & 7) * 8;
    bf16x8 o;
#pragma unroll
    for (int j = 0; j < 8; ++j) o[j] = vt[s + j][d];
    *(bf16x8*)(VT + (size_t)(bh * 64 + d) * 2048 + t0 + s) = o;
  }
}

// ---------------- flash attention, causal; 2 waves x 32 q-rows, KVBLK=64, 32x32x16 MFMA ----
__global__ __launch_bounds__(128)
void attn(const __bf16* __restrict__ Q, const __bf16* __restrict__ K,
          const __bf16* __restrict__ VT, __bf16* __restrict__ O)
{
  const int bid = blockIdx.x;
  const int bh = bid >> 5, qt = 31 - (bid & 31);   // LPT: longest q-tiles first
  const int tid = threadIdx.x;
  const int lane = tid & 63, w = tid >> 6;
  const int l31 = lane & 31, hi = lane >> 5;
  __shared__ __bf16 Ks[64 * 64];
  __shared__ __bf16 Vs[64 * 64];
  const size_t base = (size_t)bh * 2048 * 64;
  const int qrow0 = qt * 64 + w * 32;
  const int xsw = (l31 & 7) << 3;

  bf16x8 qf[4];
#pragma unroll
  for (int s = 0; s < 4; ++s)
    qf[s] = *(const bf16x8*)(Q + base + (size_t)(qrow0 + l31) * 64 + s * 16 + hi * 8);

  f32x16 oa0 = {}, oa1 = {};
  float mst = -INFINITY, lst = 0.0f;

  for (int j = 0; j <= qt; ++j) {
#pragma unroll
    for (int rnd = 0; rnd < 4; ++rnd) {
      const int c = rnd * 128 + tid;
      const int r = c >> 3;
      const int e = ((c & 7) ^ (r & 7)) * 8;
      gll16(K + base + (size_t)(j * 64 + r) * 64 + e, Ks + c * 8);
      gll16(VT + base + (size_t)r * 2048 + j * 64 + e, Vs + c * 8);
    }
    __syncthreads();

    f32x16 s0v = {}, s1v = {};
#pragma unroll
    for (int s = 0; s < 4; ++s) {
      const int co = (s * 16 + hi * 8) ^ xsw;
      bf16x8 ak0 = *(const bf16x8*)(Ks + l31 * 64 + co);
      bf16x8 ak1 = *(const bf16x8*)(Ks + (32 + l31) * 64 + co);
      s0v = __builtin_amdgcn_mfma_f32_32x32x16_bf16(ak0, qf[s], s0v, 0, 0, 0);
      s1v = __builtin_amdgcn_mfma_f32_32x32x16_bf16(ak1, qf[s], s1v, 0, 0, 0);
    }
#pragma unroll
    for (int rg = 0; rg < 16; ++rg) { s0v[rg] *= 0.125f; s1v[rg] *= 0.125f; }
    if (j == qt) {
      const int qg = qrow0 + l31;
#pragma unroll
      for (int rg = 0; rg < 16; ++rg) {
        const int kr = j * 64 + ((rg & 3) + 8 * (rg >> 2)) + 4 * hi;
        if (kr > qg) s0v[rg] = -INFINITY;
        if (kr + 32 > qg) s1v[rg] = -INFINITY;
      }
    }
    float mx = s0v[0];
#pragma unroll
    for (int rg = 1; rg < 16; ++rg) mx = fmaxf(mx, s0v[rg]);
#pragma unroll
    for (int rg = 0; rg < 16; ++rg) mx = fmaxf(mx, s1v[rg]);
    mx = fmaxf(mx, __shfl_xor(mx, 32));
    const float mnew = fmaxf(mst, mx);
    const float cf = __expf(mst - mnew);
    float rs = 0.0f;
#pragma unroll
    for (int rg = 0; rg < 16; ++rg) {
      s0v[rg] = __expf(s0v[rg] - mnew); rs += s0v[rg];
      s1v[rg] = __expf(s1v[rg] - mnew); rs += s1v[rg];
    }
    rs += __shfl_xor(rs, 32);
    lst = lst * cf + rs;
    mst = mnew;
#pragma unroll
    for (int rg = 0; rg < 16; ++rg) {
      const float cb = __shfl(cf, (rg & 3) + 8 * (rg >> 2) + 4 * hi);
      oa0[rg] *= cb; oa1[rg] *= cb;
    }
#pragma unroll
    for (int s = 0; s < 4; ++s) {
      const int br = (s & 1) * 8;
      uint32_t wA0, wA1, wB0, wB1;
      if (s < 2) {
        asm("v_cvt_pk_bf16_f32 %0, %1, %2" : "=v"(wA0) : "v"(s0v[br + 0]), "v"(s0v[br + 1]));
        asm("v_cvt_pk_bf16_f32 %0, %1, %2" : "=v"(wA1) : "v"(s0v[br + 2]), "v"(s0v[br + 3]));
        asm("v_cvt_pk_bf16_f32 %0, %1, %2" : "=v"(wB0) : "v"(s0v[br + 4]), "v"(s0v[br + 5]));
        asm("v_cvt_pk_bf16_f32 %0, %1, %2" : "=v"(wB1) : "v"(s0v[br + 6]), "v"(s0v[br + 7]));
      } else {
        asm("v_cvt_pk_bf16_f32 %0, %1, %2" : "=v"(wA0) : "v"(s1v[br + 0]), "v"(s1v[br + 1]));
        asm("v_cvt_pk_bf16_f32 %0, %1, %2" : "=v"(wA1) : "v"(s1v[br + 2]), "v"(s1v[br + 3]));
        asm("v_cvt_pk_bf16_f32 %0, %1, %2" : "=v"(wB0) : "v"(s1v[br + 4]), "v"(s1v[br + 5]));
        asm("v_cvt_pk_bf16_f32 %0, %1, %2" : "=v"(wB1) : "v"(s1v[br + 6]), "v"(s1v[br + 7]));
      }
      const u32x2 r0 = __builtin_amdgcn_permlane32_swap(wA0, wB0, false, false);
      const u32x2 r1 = __builtin_amdgcn_permlane32_swap(wA1, wB1, false, false);
      u32x4 uu; uu.x = r0.x; uu.y = r1.x; uu.z = r0.y; uu.w = r1.y;
      const bf16x8 pa = __builtin_bit_cast(bf16x8, uu);
      const int co = (s * 16 + hi * 8) ^ xsw;
      bf16x8 bv0 = *(const bf16x8*)(Vs + l31 * 64 + co);
      bf16x8 bv1 = *(const bf16x8*)(Vs + (32 + l31) * 64 + co);
      oa0 = __builtin_amdgcn_mfma_f32_32x32x16_bf16(pa, bv0, oa0, 0, 0, 0);
      oa1 = __builtin_amdgcn_mfma_f32_32x32x16_bf16(pa, bv1, oa1, 0, 0, 0);
    }
    __syncthreads();
  }
  const float inv = 1.0f / lst;
  const int b = bh >> 4, hd = bh & 15;
#pragma unroll
  for (int rg = 0; rg < 16; ++rg) {
    const int cr = (rg & 3) + 8 * (rg >> 2) + 4 * hi;
    const float ib = __shfl(inv, cr);
    const int qr = qrow0 + cr;
    O[(size_t)(b * 2048 + qr) * 1024 + hd * 64 + l31]      = (__bf16)(oa0[rg] * ib);
    O[(size_t)(b * 2048 + qr) * 1024 + hd * 64 + 32 + l31] = (__bf16)(oa1[rg] * ib);
  }
}

// ---------------- host ----------------
extern "C" void kernel_launch(void* const* d_in, const int* in_sizes, int n_in,
                              void* d_out, int out_size, void* d_ws, size_t ws_size,
                              hipStream_t stream)
{
  const float* x      = (const float*)d_in[0];
  const float* ln1_g  = (const float*)d_in[1];
  const float* ln1_b  = (const float*)d_in[2];
  const float* qkv_w  = (const float*)d_in[3];
  const float* qkv_b  = (const float*)d_in[4];
  const float* proj_w = (const float*)d_in[5];
  const float* proj_b = (const float*)d_in[6];
  const float* ln2_g  = (const float*)d_in[7];
  const float* ln2_b  = (const float*)d_in[8];
  const float* mlp_w1 = (const float*)d_in[9];
  const float* mlp_b1 = (const float*)d_in[10];
  const float* mlp_w2 = (const float*)d_in[11];
  const float* mlp_b2 = (const float*)d_in[12];

  // Workspace (117440512 B):
  //  [0,25165824)        weights (persistent)
  //  [25165824,41943040) x2 fp32
  //  [41943040,75497472) h1 | qkv@50331648 | partP fp32 32MB | part2 bf16 32MB (sequential liveness)
  //  [75497472,...)      Qb,Kb,VTb,attO | h2@75497472 | act1@83886080 (32MB, ends 117440512)
  char* ws = (char*)d_ws;
  __bf16* qkvT  = (__bf16*)(ws + 0);
  __bf16* projT = (__bf16*)(ws + 6291456);
  __bf16* w1T   = (__bf16*)(ws + 8388608);
  __bf16* w2T   = (__bf16*)(ws + 16777216);
  float*  x2    = (float*) (ws + 25165824);
  __bf16* h1    = (__bf16*)(ws + 41943040);
  float*  partP = (float*) (ws + 41943040);
  __bf16* part2 = (__bf16*)(ws + 41943040);
  __bf16* qkv   = (__bf16*)(ws + 50331648);
  __bf16* Qb    = (__bf16*)(ws + 75497472);
  __bf16* h2    = (__bf16*)(ws + 75497472);
  __bf16* Kb    = (__bf16*)(ws + 83886080);
  __bf16* act1  = (__bf16*)(ws + 83886080);
  __bf16* VTb   = (__bf16*)(ws + 92274688);
  __bf16* attO  = (__bf16*)(ws + 100663296);

  convT_all<<<3072, 256, 0, stream>>>(qkv_w, qkvT, proj_w, projT, mlp_w1, w1T, mlp_w2, w2T);

  ln_rows<<<4096, 256, 0, stream>>>(x, ln1_g, ln1_b, h1);
  gemm_bt<EPI_BF16><<<dim3(24, 32), 256, 0, stream>>>(h1, qkvT, qkv_b, nullptr, qkv, 4096, 3072, 1024);
  rearrange<<<1024, 256, 0, stream>>>(qkv, Qb, Kb, VTb);
  attn<<<1024, 128, 0, stream>>>(Qb, Kb, VTb, attO);
  gemm_bt<EPI_PART><<<dim3(8, 32, 2), 256, 0, stream>>>(attO, projT, nullptr, nullptr, partP, 4096, 1024, 1024);
  reduce2<<<4096, 256, 0, stream>>>(partP, proj_b, x, x2, 4096 * 1024, 1024);
  ln_rows<<<4096, 256, 0, stream>>>(x2, ln2_g, ln2_b, h2);
  gemm_bt<EPI_GELU><<<dim3(32, 32), 256, 0, stream>>>(h2, w1T, mlp_b1, nullptr, act1, 4096, 4096, 1024);
  gemm_bt<EPI_PARTB><<<dim3(8, 32, 4), 256, 0, stream>>>(act1, w2T, nullptr, nullptr, part2, 4096, 1024, 4096);
  reduce4<<<2048, 256, 0, stream>>>(part2, mlp_b2, x2, (float*)d_out, 4096 * 1024, 1024);
}

// Round 7
// 409.298 us; speedup vs baseline: 1.3262x; 1.0137x over previous
//
#include <hip/hip_runtime.h>
#include <hip/hip_bf16.h>
#include <cstdint>

typedef __attribute__((ext_vector_type(4))) float f32x4;
typedef __attribute__((ext_vector_type(16))) float f32x16;
typedef __attribute__((ext_vector_type(8))) __bf16 bf16x8;
typedef __attribute__((ext_vector_type(4))) __bf16 bf16x4;
typedef __attribute__((ext_vector_type(4))) uint32_t u32x4;
typedef __attribute__((ext_vector_type(2))) unsigned int u32x2;

#define EPI_BF16  0
#define EPI_GELU  1
#define EPI_RES   2
#define EPI_PART  3
#define EPI_PARTB 4

__device__ __forceinline__ void gll16(const void* g, void* l) {
  __builtin_amdgcn_global_load_lds((__attribute__((address_space(1))) void*)(g),
                                   (__attribute__((address_space(3))) void*)(l), 16, 0, 0);
}

// ---------------- weight convert+transpose, all 4 weights in one launch ----------------
__global__ __launch_bounds__(256)
void convT_all(const float* __restrict__ W0, __bf16* __restrict__ T0,
               const float* __restrict__ W1, __bf16* __restrict__ T1,
               const float* __restrict__ W2, __bf16* __restrict__ T2,
               const float* __restrict__ W3, __bf16* __restrict__ T3)
{
  __shared__ __bf16 t[64][72];
  const int bid = blockIdx.x;
  const float* W; __bf16* WT; int Kd, Nd, nx, lb;
  if (bid < 768)       { W = W0; WT = T0; Kd = 1024; Nd = 3072; nx = 48; lb = bid; }
  else if (bid < 1024) { W = W1; WT = T1; Kd = 1024; Nd = 1024; nx = 16; lb = bid - 768; }
  else if (bid < 2048) { W = W2; WT = T2; Kd = 1024; Nd = 4096; nx = 64; lb = bid - 1024; }
  else                 { W = W3; WT = T3; Kd = 4096; Nd = 1024; nx = 16; lb = bid - 2048; }
  const int tid = threadIdx.x;
  const int n0 = (lb % nx) * 64, k0 = (lb / nx) * 64;
#pragma unroll
  for (int i = 0; i < 4; ++i) {
    const int c = i * 256 + tid;
    const int r = c >> 4, cc = (c & 15) * 4;
    const float4 v = *(const float4*)(W + (size_t)(k0 + r) * Nd + n0 + cc);
    bf16x4 tv; tv[0] = (__bf16)v.x; tv[1] = (__bf16)v.y; tv[2] = (__bf16)v.z; tv[3] = (__bf16)v.w;
    *(bf16x4*)&t[r][cc] = tv;
  }
  __syncthreads();
#pragma unroll
  for (int i = 0; i < 2; ++i) {
    const int c = i * 256 + tid;
    const int n = c >> 3, s = (c & 7) * 8;
    bf16x8 o;
#pragma unroll
    for (int j = 0; j < 8; ++j) o[j] = t[s + j][n];
    *(bf16x8*)(WT + (size_t)(n0 + n) * Kd + k0 + s) = o;
  }
}

// ---------------- LayerNorm rows of 1024, fp32 in -> bf16 out ----------------
__global__ __launch_bounds__(256)
void ln_rows(const float* __restrict__ x, const float* __restrict__ g,
             const float* __restrict__ b, __bf16* __restrict__ out)
{
  const int row = blockIdx.x;
  const int tid = threadIdx.x;
  const float4 v = *(const float4*)(x + (size_t)row * 1024 + tid * 4);
  float s = v.x + v.y + v.z + v.w;
  float q = v.x * v.x + v.y * v.y + v.z * v.z + v.w * v.w;
#pragma unroll
  for (int o = 32; o; o >>= 1) { s += __shfl_xor(s, o); q += __shfl_xor(q, o); }
  __shared__ float red[8];
  const int wid = tid >> 6;
  if ((tid & 63) == 0) { red[wid] = s; red[4 + wid] = q; }
  __syncthreads();
  s = red[0] + red[1] + red[2] + red[3];
  q = red[4] + red[5] + red[6] + red[7];
  const float mu = s * (1.0f / 1024.0f);
  const float var = q * (1.0f / 1024.0f) - mu * mu;
  const float rs = rsqrtf(var + 1e-5f);
  bf16x4 o4;
#pragma unroll
  for (int i = 0; i < 4; ++i) {
    const int c = tid * 4 + i;
    const float xv = (&v.x)[i];
    o4[i] = (__bf16)((xv - mu) * rs * g[c] + b[c]);
  }
  *(bf16x4*)(out + (size_t)row * 1024 + tid * 4) = o4;
}

// ---------------- GEMM: C[M,N] = A[M,K](bf16) * W, W given as WT[N,K](bf16) ----------------
// 2-phase pipeline: LDS double-buffer, stage(t+1) issued BEFORE compute(t), one barrier/iter.
// Conflict-free LDS via pre-swizzled global source + matching read XOR. XCD block swizzle.
template<int EPI>
__global__ __launch_bounds__(256)
void gemm_bt(const __bf16* __restrict__ A, const __bf16* __restrict__ BT,
             const float* __restrict__ bias, const float* __restrict__ R,
             void* __restrict__ Out, int M, int N, int K)
{
  const int tid = threadIdx.x;
  const int lane = tid & 63, wid = tid >> 6;
  const int l15 = lane & 15, lg = lane >> 4;
  const int wm = (wid >> 1) * 64, wn = (wid & 1) * 64;
  const int nwg = gridDim.x * gridDim.y;
  const int hw = blockIdx.y * gridDim.x + blockIdx.x;
  const int logical = (hw & 7) * (nwg >> 3) + (hw >> 3);
  const int rowBase = (logical / gridDim.x) * 128;
  const int colBase = (logical % gridDim.x) * 128;
  const int kLen = K / gridDim.z;
  const int kBeg = blockIdx.z * kLen;
  __shared__ __bf16 As[2][128 * 32];
  __shared__ __bf16 Bs[2][128 * 32];
  f32x4 acc[4][4] = {};
  const int fsw = ((l15 >> 1) & 3) << 3;

  auto STAGE = [&](int buf, int k0) {
#pragma unroll
    for (int i = 0; i < 2; ++i) {
      const int c = i * 256 + tid;
      const int r = c >> 2;
      const int s = ((c & 3) ^ ((r >> 1) & 3)) * 8;
      gll16(A + (size_t)(rowBase + r) * K + (k0 + s), &As[buf][c * 8]);
      gll16(BT + (size_t)(colBase + r) * K + (k0 + s), &Bs[buf][c * 8]);
    }
  };

  STAGE(0, kBeg);
  __syncthreads();
  int cur = 0;
  const int kEnd = kBeg + kLen;
  for (int k0 = kBeg; k0 < kEnd; k0 += 32) {
    if (k0 + 32 < kEnd) STAGE(cur ^ 1, k0 + 32);
    bf16x8 af[4], bfr[4];
#pragma unroll
    for (int m = 0; m < 4; ++m) af[m] = *(const bf16x8*)(&As[cur][(wm + m * 16 + l15) * 32 + (lg * 8 ^ fsw)]);
#pragma unroll
    for (int n = 0; n < 4; ++n) bfr[n] = *(const bf16x8*)(&Bs[cur][(wn + n * 16 + l15) * 32 + (lg * 8 ^ fsw)]);
#pragma unroll
    for (int m = 0; m < 4; ++m)
#pragma unroll
      for (int n = 0; n < 4; ++n)
        acc[m][n] = __builtin_amdgcn_mfma_f32_16x16x32_bf16(af[m], bfr[n], acc[m][n], 0, 0, 0);
    __syncthreads();
    cur ^= 1;
  }
#pragma unroll
  for (int m = 0; m < 4; ++m) {
#pragma unroll
    for (int n = 0; n < 4; ++n) {
      const int col = colBase + wn + n * 16 + l15;
      float bb = 0.0f;
      if constexpr (EPI != EPI_PART && EPI != EPI_PARTB) bb = bias[col];
#pragma unroll
      for (int i = 0; i < 4; ++i) {
        const int row = rowBase + wm + m * 16 + lg * 4 + i;
        float v = acc[m][n][i] + bb;
        if constexpr (EPI == EPI_GELU) {
          v = 0.5f * v * (1.0f + erff(v * 0.70710678118654752f));
          ((__bf16*)Out)[(size_t)row * N + col] = (__bf16)v;
        } else if constexpr (EPI == EPI_BF16) {
          ((__bf16*)Out)[(size_t)row * N + col] = (__bf16)v;
        } else if constexpr (EPI == EPI_RES) {
          v += R[(size_t)row * N + col];
          ((float*)Out)[(size_t)row * N + col] = v;
        } else if constexpr (EPI == EPI_PART) {
          ((float*)Out)[((size_t)blockIdx.z * M + row) * N + col] = v;
        } else {
          ((__bf16*)Out)[((size_t)blockIdx.z * M + row) * N + col] = (__bf16)v;
        }
      }
    }
  }
}

// ---------------- split-K reduce (2 fp32 partials): out = P0+P1+bias+R ----------------
__global__ __launch_bounds__(256)
void reduce2(const float* __restrict__ P, const float* __restrict__ bias,
             const float* __restrict__ R, float* __restrict__ Out, int MN, int N)
{
  const size_t e = ((size_t)blockIdx.x * 256 + threadIdx.x) * 4;
  const float4 a = *(const float4*)(P + e);
  const float4 b = *(const float4*)(P + (size_t)MN + e);
  const float4 r = *(const float4*)(R + e);
  const float4 bb = *(const float4*)(bias + (e & (size_t)(N - 1)));
  float4 o;
  o.x = a.x + b.x + r.x + bb.x;
  o.y = a.y + b.y + r.y + bb.y;
  o.z = a.z + b.z + r.z + bb.z;
  o.w = a.w + b.w + r.w + bb.w;
  *(float4*)(Out + e) = o;
}

// ---------------- split-K reduce (4 bf16 partials): out = sum P + bias + R ----------------
__global__ __launch_bounds__(256)
void reduce4(const __bf16* __restrict__ P, const float* __restrict__ bias,
             const float* __restrict__ R, float* __restrict__ Out, int MN, int N)
{
  const size_t e = ((size_t)blockIdx.x * 256 + threadIdx.x) * 8;
  float s[8];
#pragma unroll
  for (int i = 0; i < 8; ++i) s[i] = 0.0f;
#pragma unroll
  for (int p = 0; p < 4; ++p) {
    const bf16x8 v = *(const bf16x8*)(P + (size_t)p * MN + e);
#pragma unroll
    for (int i = 0; i < 8; ++i) s[i] += (float)v[i];
  }
  const size_t col = e & (size_t)(N - 1);
  const float4 r0 = *(const float4*)(R + e),       r1 = *(const float4*)(R + e + 4);
  const float4 b0 = *(const float4*)(bias + col),  b1 = *(const float4*)(bias + col + 4);
  float4 o0, o1;
  o0.x = s[0] + r0.x + b0.x; o0.y = s[1] + r0.y + b0.y;
  o0.z = s[2] + r0.z + b0.z; o0.w = s[3] + r0.w + b0.w;
  o1.x = s[4] + r1.x + b1.x; o1.y = s[5] + r1.y + b1.y;
  o1.z = s[6] + r1.z + b1.z; o1.w = s[7] + r1.w + b1.w;
  *(float4*)(Out + e)     = o0;
  *(float4*)(Out + e + 4) = o1;
}

// ---------------- rearrange qkv[4096,3072] -> Q[bh,t,d], K[bh,t,d], VT[bh,d,t] ----------------
__global__ __launch_bounds__(256)
void rearrange(const __bf16* __restrict__ qkv, __bf16* __restrict__ Q,
               __bf16* __restrict__ Kb, __bf16* __restrict__ VT)
{
  __shared__ __bf16 vt[64][72];
  const int tid = threadIdx.x;
  const int bid = blockIdx.x;
  const int bh = bid >> 5, tt = bid & 31;
  const int b = bh >> 4, h = bh & 15;
  const int t0 = tt * 64;
#pragma unroll
  for (int i = 0; i < 2; ++i) {
    const int c = i * 256 + tid;
    const int tk = c >> 3, d0 = (c & 7) * 8;
    const size_t srow = (size_t)(b * 2048 + t0 + tk) * 3072 + h * 64 + d0;
    const size_t drow = (size_t)(bh * 2048 + t0 + tk) * 64 + d0;
    *(bf16x8*)(Q + drow) = *(const bf16x8*)(qkv + srow);
    *(bf16x8*)(Kb + drow) = *(const bf16x8*)(qkv + srow + 1024);
    *(bf16x8*)&vt[tk][d0] = *(const bf16x8*)(qkv + srow + 2048);
  }
  __syncthreads();
#pragma unroll
  for (int i = 0; i < 2; ++i) {
    const int c = i * 256 + tid;
    const int d = c >> 3, s = (c & 7) * 8;
    bf16x8 o;
#pragma unroll
    for (int j = 0; j < 8; ++j) o[j] = vt[s + j][d];
    *(bf16x8*)(VT + (size_t)(bh * 64 + d) * 2048 + t0 + s) = o;
  }
}

// ---------------- flash attention, causal; 4 waves x 32 q-rows (QBLK=128), KVBLK=64 ----------
// 32x32x16 MFMA, swapped QK^T, in-register softmax in exp2 domain (scale folded into FMA),
// defer-max (T13, THR=8 in log2), K/V LDS double-buffered 2-phase staging.
__global__ __launch_bounds__(256)
void attn(const __bf16* __restrict__ Q, const __bf16* __restrict__ K,
          const __bf16* __restrict__ VT, __bf16* __restrict__ O)
{
  const int bid = blockIdx.x;
  const int bh = bid >> 4, qt = 15 - (bid & 15);   // LPT: longest q-tiles first
  const int tid = threadIdx.x;
  const int lane = tid & 63, w = tid >> 6;
  const int l31 = lane & 31, hi = lane >> 5;
  __shared__ __bf16 Ks[2][64 * 64];
  __shared__ __bf16 Vs[2][64 * 64];
  const size_t base = (size_t)bh * 2048 * 64;
  const int qrow0 = qt * 128 + w * 32;
  const int jd = qrow0 >> 6;          // this wave's diagonal KV tile
  const int jmax = 2 * qt + 1;        // block's last KV tile
  const int xsw = (l31 & 7) << 3;
  const float KS = 0.18033688011112042f;  // 0.125 * log2(e)

  bf16x8 qf[4];
#pragma unroll
  for (int s = 0; s < 4; ++s)
    qf[s] = *(const bf16x8*)(Q + base + (size_t)(qrow0 + l31) * 64 + s * 16 + hi * 8);

  f32x16 oa0 = {}, oa1 = {};
  float ms = -INFINITY, lst = 0.0f;

  auto STAGE = [&](int buf, int j) {
#pragma unroll
    for (int i = 0; i < 2; ++i) {
      const int c = i * 256 + tid;
      const int r = c >> 3;
      const int e = ((c & 7) ^ (r & 7)) * 8;
      gll16(K + base + (size_t)(j * 64 + r) * 64 + e, &Ks[buf][c * 8]);
      gll16(VT + base + (size_t)r * 2048 + j * 64 + e, &Vs[buf][c * 8]);
    }
  };

  STAGE(0, 0);
  __syncthreads();
  int cur = 0;
  for (int j = 0; j <= jmax; ++j) {
    if (j < jmax) STAGE(cur ^ 1, j + 1);
    if (j <= jd) {
      // S^T = K · Q^T : col(lane&31)=q, row(crow(reg,hi))=key
      f32x16 s0v = {}, s1v = {};
#pragma unroll
      for (int s = 0; s < 4; ++s) {
        const int co = (s * 16 + hi * 8) ^ xsw;
        bf16x8 ak0 = *(const bf16x8*)(&Ks[cur][l31 * 64 + co]);
        bf16x8 ak1 = *(const bf16x8*)(&Ks[cur][(32 + l31) * 64 + co]);
        s0v = __builtin_amdgcn_mfma_f32_32x32x16_bf16(ak0, qf[s], s0v, 0, 0, 0);
        s1v = __builtin_amdgcn_mfma_f32_32x32x16_bf16(ak1, qf[s], s1v, 0, 0, 0);
      }
      if (j == jd) {
        const int qg = qrow0 + l31;
#pragma unroll
        for (int rg = 0; rg < 16; ++rg) {
          const int kr = j * 64 + ((rg & 3) + 8 * (rg >> 2)) + 4 * hi;
          if (kr > qg) s0v[rg] = -INFINITY;
          if (kr + 32 > qg) s1v[rg] = -INFINITY;
        }
      }
      // row max (raw domain), then scaled
      float mx = fmaxf(s0v[0], s1v[0]);
#pragma unroll
      for (int rg = 1; rg < 16; ++rg) mx = fmaxf(mx, fmaxf(s0v[rg], s1v[rg]));
      mx = fmaxf(mx, __shfl_xor(mx, 32));
      const float mxs = mx * KS;
      // defer-max: only rescale when max grew by > 8 (log2 units)
      if (!__all(mxs - ms <= 8.0f)) {
        const float msn = fmaxf(ms, mxs);
        const float cf = exp2f(ms - msn);
        lst *= cf;
        ms = msn;
#pragma unroll
        for (int rg = 0; rg < 16; ++rg) {
          const float cb = __shfl(cf, (rg & 3) + 8 * (rg >> 2) + 4 * hi);
          oa0[rg] *= cb; oa1[rg] *= cb;
        }
      }
      float rs = 0.0f;
#pragma unroll
      for (int rg = 0; rg < 16; ++rg) {
        const float p0 = exp2f(fmaf(s0v[rg], KS, -ms));
        const float p1 = exp2f(fmaf(s1v[rg], KS, -ms));
        s0v[rg] = p0; s1v[rg] = p1;
        rs += p0 + p1;
      }
      rs += __shfl_xor(rs, 32);
      lst += rs;
      // P -> bf16 A-frags (cvt_pk + permlane32_swap), then O += P·V
#pragma unroll
      for (int s = 0; s < 4; ++s) {
        const int br = (s & 1) * 8;
        uint32_t wA0, wA1, wB0, wB1;
        if (s < 2) {
          asm("v_cvt_pk_bf16_f32 %0, %1, %2" : "=v"(wA0) : "v"(s0v[br + 0]), "v"(s0v[br + 1]));
          asm("v_cvt_pk_bf16_f32 %0, %1, %2" : "=v"(wA1) : "v"(s0v[br + 2]), "v"(s0v[br + 3]));
          asm("v_cvt_pk_bf16_f32 %0, %1, %2" : "=v"(wB0) : "v"(s0v[br + 4]), "v"(s0v[br + 5]));
          asm("v_cvt_pk_bf16_f32 %0, %1, %2" : "=v"(wB1) : "v"(s0v[br + 6]), "v"(s0v[br + 7]));
        } else {
          asm("v_cvt_pk_bf16_f32 %0, %1, %2" : "=v"(wA0) : "v"(s1v[br + 0]), "v"(s1v[br + 1]));
          asm("v_cvt_pk_bf16_f32 %0, %1, %2" : "=v"(wA1) : "v"(s1v[br + 2]), "v"(s1v[br + 3]));
          asm("v_cvt_pk_bf16_f32 %0, %1, %2" : "=v"(wB0) : "v"(s1v[br + 4]), "v"(s1v[br + 5]));
          asm("v_cvt_pk_bf16_f32 %0, %1, %2" : "=v"(wB1) : "v"(s1v[br + 6]), "v"(s1v[br + 7]));
        }
        const u32x2 r0 = __builtin_amdgcn_permlane32_swap(wA0, wB0, false, false);
        const u32x2 r1 = __builtin_amdgcn_permlane32_swap(wA1, wB1, false, false);
        u32x4 uu; uu.x = r0.x; uu.y = r1.x; uu.z = r0.y; uu.w = r1.y;
        const bf16x8 pa = __builtin_bit_cast(bf16x8, uu);
        const int co = (s * 16 + hi * 8) ^ xsw;
        bf16x8 bv0 = *(const bf16x8*)(&Vs[cur][l31 * 64 + co]);
        bf16x8 bv1 = *(const bf16x8*)(&Vs[cur][(32 + l31) * 64 + co]);
        oa0 = __builtin_amdgcn_mfma_f32_32x32x16_bf16(pa, bv0, oa0, 0, 0, 0);
        oa1 = __builtin_amdgcn_mfma_f32_32x32x16_bf16(pa, bv1, oa1, 0, 0, 0);
      }
    }
    __syncthreads();
    cur ^= 1;
  }
  const float inv = 1.0f / lst;
  const int b = bh >> 4, hd = bh & 15;
#pragma unroll
  for (int rg = 0; rg < 16; ++rg) {
    const int cr = (rg & 3) + 8 * (rg >> 2) + 4 * hi;
    const float ib = __shfl(inv, cr);
    const int qr = qrow0 + cr;
    O[(size_t)(b * 2048 + qr) * 1024 + hd * 64 + l31]      = (__bf16)(oa0[rg] * ib);
    O[(size_t)(b * 2048 + qr) * 1024 + hd * 64 + 32 + l31] = (__bf16)(oa1[rg] * ib);
  }
}

// ---------------- host ----------------
extern "C" void kernel_launch(void* const* d_in, const int* in_sizes, int n_in,
                              void* d_out, int out_size, void* d_ws, size_t ws_size,
                              hipStream_t stream)
{
  const float* x      = (const float*)d_in[0];
  const float* ln1_g  = (const float*)d_in[1];
  const float* ln1_b  = (const float*)d_in[2];
  const float* qkv_w  = (const float*)d_in[3];
  const float* qkv_b  = (const float*)d_in[4];
  const float* proj_w = (const float*)d_in[5];
  const float* proj_b = (const float*)d_in[6];
  const float* ln2_g  = (const float*)d_in[7];
  const float* ln2_b  = (const float*)d_in[8];
  const float* mlp_w1 = (const float*)d_in[9];
  const float* mlp_b1 = (const float*)d_in[10];
  const float* mlp_w2 = (const float*)d_in[11];
  const float* mlp_b2 = (const float*)d_in[12];

  char* ws = (char*)d_ws;
  __bf16* qkvT  = (__bf16*)(ws + 0);
  __bf16* projT = (__bf16*)(ws + 6291456);
  __bf16* w1T   = (__bf16*)(ws + 8388608);
  __bf16* w2T   = (__bf16*)(ws + 16777216);
  float*  x2    = (float*) (ws + 25165824);
  __bf16* h1    = (__bf16*)(ws + 41943040);
  float*  partP = (float*) (ws + 41943040);
  __bf16* part2 = (__bf16*)(ws + 41943040);
  __bf16* qkv   = (__bf16*)(ws + 50331648);
  __bf16* Qb    = (__bf16*)(ws + 75497472);
  __bf16* h2    = (__bf16*)(ws + 75497472);
  __bf16* Kb    = (__bf16*)(ws + 83886080);
  __bf16* act1  = (__bf16*)(ws + 83886080);
  __bf16* VTb   = (__bf16*)(ws + 92274688);
  __bf16* attO  = (__bf16*)(ws + 100663296);

  convT_all<<<3072, 256, 0, stream>>>(qkv_w, qkvT, proj_w, projT, mlp_w1, w1T, mlp_w2, w2T);

  ln_rows<<<4096, 256, 0, stream>>>(x, ln1_g, ln1_b, h1);
  gemm_bt<EPI_BF16><<<dim3(24, 32), 256, 0, stream>>>(h1, qkvT, qkv_b, nullptr, qkv, 4096, 3072, 1024);
  rearrange<<<1024, 256, 0, stream>>>(qkv, Qb, Kb, VTb);
  attn<<<512, 256, 0, stream>>>(Qb, Kb, VTb, attO);
  gemm_bt<EPI_PART><<<dim3(8, 32, 2), 256, 0, stream>>>(attO, projT, nullptr, nullptr, partP, 4096, 1024, 1024);
  reduce2<<<4096, 256, 0, stream>>>(partP, proj_b, x, x2, 4096 * 1024, 1024);
  ln_rows<<<4096, 256, 0, stream>>>(x2, ln2_g, ln2_b, h2);
  gemm_bt<EPI_GELU><<<dim3(32, 32), 256, 0, stream>>>(h2, w1T, mlp_b1, nullptr, act1, 4096, 4096, 1024);
  gemm_bt<EPI_PARTB><<<dim3(8, 32, 4), 256, 0, stream>>>(act1, w2T, nullptr, nullptr, part2, 4096, 1024, 4096);
  reduce4<<<2048, 256, 0, stream>>>(part2, mlp_b2, x2, (float*)d_out, 4096 * 1024, 1024);
}